// Round 22
// baseline (656.452 us; speedup 1.0000x reference)
//
#include <hip/hip_runtime.h>
#include <hip/hip_bf16.h>
#include <cstdint>
#include <cstddef>

#define B_    16
#define L_    512
#define LH    511
#define RTOT  (B_*LH)      // 8176 rows
#define DM    256
#define DFEAT 1024
#define NG    64
#define GPDIM 64
#define NENT  8000
#define NRELS 100
#define RS    8000         // f32 row stride inside d_out
#define RS2   16000        // bf16 row stride inside d_out

// f32 column slots inside each row's 8000-float span of d_out
#define COL_X     0
#define COL_CUR   256
#define COL_Q     512
#define COL_K     768
#define COL_V     1024
#define COL_ATTN  1280
#define COL_FF    1536     // flatF: enc_out(512) | s_emb(256) | r_emb(256)
#define COL_GATH  2560     // 64 wide -> merged = cols [1536, 2624) K=1088 contiguous
#define COL_GSUM  3000     // rows 0..1023 only, 1024 wide
#define COL_GCNT  4100     // rows 0..1023, 1 float
#define COL_GP    4200     // rows 0..1023, 64 wide
#define COL_GOUT  4300     // rows 0..1023, 64 wide
#define COL_FLAG  5000     // row 0 only
// bf16 regions (bf16-element offsets within a row, stride RS2)
#define BCOL_ENCW 5248     // = 2*2624 : encoder Wt, rows 0..2047 (8 slots x 256), 512 bf16 wide
#define BCOL_MGWT 11104    // = 2*5552 : mgWt rows 0..1023, 1088 bf16
#define BCOL_MGA  12192    // = 2*6096 : merged-A bf16 copy, all rows, 1088 bf16 (dead before F1 writes)
#define BCOL_WT   13824    // = 2*6912 : Wt rows 0..6911, 1024 bf16
#define BCOL_ENH  14848    // = 2*7424 : enh bf16, all rows, 1024 bf16 (fallback path only)
#define N1        6912     // F1 covers out cols [0, 6912); tail covers [6912, 8000)

// ---- d_ws layouts ----
// v1 (ws_ok):  [Bt 1088x1024 bf16][K][V]           (needs 10.6 MB)
#define WS_OFF_K  2228224ull
#define WS_OFF_V  (WS_OFF_K + 4186112ull)
#define WS_NEED2  (WS_OFF_V + 4194304ull)
// v2 (ws_ok3): [Bt 1152x1024 bf16][ENH 8176x1024 bf16, K/V overlap inside]
#define WS2_BT    0ull
#define WS2_ENH   2359296ull
#define WS2_K     WS2_ENH
#define WS2_V     (WS2_K + 4186112ull)
#define WS_NEED3  (WS2_ENH + 16744448ull)   // 19,103,744 bytes

static constexpr float LN1E4_OVER_128 = 0.07195578415606394f; // ln(10000)/128

typedef __attribute__((ext_vector_type(8))) short short8;
typedef __attribute__((ext_vector_type(4))) short sshort4;
typedef __attribute__((ext_vector_type(4))) float f32x4;
typedef __attribute__((ext_vector_type(2))) float f32x2;

__device__ __forceinline__ short bf16b(float x){
  union { __hip_bfloat16 h; short s; } u; u.h = __float2bfloat16(x); return u.s;
}

// fast softplus: hw v_exp_f32 / v_log_f32 (~7 VALU ops vs ~55 for libm)
__device__ __forceinline__ float fast_softplus(float v) {
  return fmaxf(v, 0.f) + __logf(1.0f + __expf(-fabsf(v)));
}

// async global->LDS copy, 16B per lane. LDS dest is wave-uniform base +
// lane*16 (linear); global src is per-lane (we pre-swizzle it).
__device__ __forceinline__ void gload16(const void* g, void* l) {
  __builtin_amdgcn_global_load_lds(
      (const __attribute__((address_space(1))) unsigned int*)g,
      (__attribute__((address_space(3))) unsigned int*)l, 16, 0, 0);
}

// ---------------- mask dtype autodetect (bool(1B) vs int32) ----------------
__global__ __launch_bounds__(256) void k_detect(const unsigned int* __restrict__ m,
                                                float* __restrict__ outbuf) {
  __shared__ int bad;
  if (threadIdx.x == 0) bad = 0;
  __syncthreads();
  int local = 0;
  for (int i = threadIdx.x; i < 2048; i += 256)
    if (m[i] > 1u) local = 1;
  if (local) bad = 1;
  __syncthreads();
  if (threadIdx.x == 0) ((int*)outbuf)[COL_FLAG] = bad;   // 1 => byte-bool layout
}

__device__ __forceinline__ int mask_at(const void* m, int idx, int boolmode) {
  return boolmode ? (int)((const unsigned char*)m)[idx] : ((const int*)m)[idx];
}

// ---------------- x,cur build ----------------
__global__ __launch_bounds__(256) void k_build_x_cur(
    const int* __restrict__ objs, const float* __restrict__ times,
    const float* __restrict__ dts, const float* __restrict__ obj_embed,
    float* __restrict__ out)
{
  int bt = blockIdx.x;
  int b = bt / LH, t = bt - b * LH;
  int d = threadIdx.x;
  int i = d & 127;
  float freq = expf(-(float)i * LN1E4_OVER_128);
  float t0 = times[b*L_ + t];
  float t1 = times[b*L_ + t + 1];
  float dtv = dts[b*L_ + t];
  float a0 = t0*freq, ad = dtv*freq, a1 = t1*freq;
  bool lo = (d < 128);
  float te0 = lo ? sinf(a0) : cosf(a0);
  float ted = lo ? sinf(ad) : cosf(ad);
  float te1 = lo ? sinf(a1) : cosf(a1);
  int obj = objs[b*L_ + t];
  out[(size_t)bt*RS + COL_X   + d] = obj_embed[(size_t)obj*DM + d] + te0 + ted;
  out[(size_t)bt*RS + COL_CUR + d] = te1;
}

// ---------------- bf16 MFMA GEMM, direct-from-global ----------------------
// EPI 2: Cf += acc (residual, no bias); aux[grow*ldaux + auxoff + col] = new Cf
// EPI 3: Cf = acc (plain f32, no bias)
template<bool AF32, int EPI>
__global__ __launch_bounds__(256) void gemm_mfma(
    const void* __restrict__ Aptr, long strideA,
    const short* __restrict__ Bt, long strideB,
    const float* __restrict__ bias,
    float* __restrict__ Cf, long strideC,
    __hip_bfloat16* __restrict__ Cb, long strideCb,
    float* __restrict__ aux, long ldaux, int auxoff,
    int M, int K)
{
  int lane = threadIdx.x & 63;
  int wid  = threadIdx.x >> 6;
  int wm = wid >> 1, wn = wid & 1;
  int r15 = lane & 15, koct = lane >> 4;
  int m0 = blockIdx.y*128 + wm*64;
  int n0 = blockIdx.x*128 + wn*64;
  f32x4 acc[4][4] = {};
  int ar[4];
  #pragma unroll
  for (int mf = 0; mf < 4; ++mf) {
    int r = m0 + mf*16 + r15;
    ar[mf] = r < M ? r : M-1;
  }
  const short* Ab = (const short*)Aptr;
  const float* Af = (const float*)Aptr;
  for (int k0 = 0; k0 < K; k0 += 32) {
    int kk = k0 + koct*8;
    short8 a[4], b[4];
    #pragma unroll
    for (int mf = 0; mf < 4; ++mf) {
      if (AF32) {
        const float* p = Af + (size_t)ar[mf]*strideA + kk;
        f32x4 lo = *(const f32x4*)p;
        f32x4 hi = *(const f32x4*)(p + 4);
        short8 t;
        #pragma unroll
        for (int i = 0; i < 4; ++i) { t[i] = bf16b(lo[i]); t[i+4] = bf16b(hi[i]); }
        a[mf] = t;
      } else {
        a[mf] = *(const short8*)(Ab + (size_t)ar[mf]*strideA + kk);
      }
    }
    #pragma unroll
    for (int nf = 0; nf < 4; ++nf) {
      int n = n0 + nf*16 + r15;
      b[nf] = *(const short8*)(Bt + (size_t)n*strideB + kk);
    }
    #pragma unroll
    for (int mf = 0; mf < 4; ++mf)
      #pragma unroll
      for (int nf = 0; nf < 4; ++nf)
        acc[mf][nf] = __builtin_amdgcn_mfma_f32_16x16x32_bf16(a[mf], b[nf], acc[mf][nf], 0, 0, 0);
  }
  #pragma unroll
  for (int mf = 0; mf < 4; ++mf) {
    #pragma unroll
    for (int r = 0; r < 4; ++r) {
      int grow = m0 + mf*16 + koct*4 + r;
      if (grow >= M) continue;
      #pragma unroll
      for (int nf = 0; nf < 4; ++nf) {
        int gcol = n0 + nf*16 + r15;
        float v = acc[mf][nf][r];
        size_t ci = (size_t)grow*strideC + gcol;
        if (EPI == 2) {
          v += Cf[ci];
          Cf[ci] = v;
          aux[(size_t)grow*ldaux + auxoff + gcol] = v;
        } else {
          Cf[ci] = v;
        }
      }
    }
  }
}

// ---------------- LDS-staged bf16 MFMA GEMM (m97 structure) ---------------
// EPI 0: Cf = softplus(acc+bias), nontemporal (final output, never re-read)
// EPI 1: Cb = bf16(acc+bias); optional Cb2 dual-store
// Store guard: gcol < N (B rows may be padded past N).
template<int EPI>
__global__ __launch_bounds__(256) void gemm_mfma_lds(
    const short* __restrict__ A, long strideA,
    const short* __restrict__ Bt, long strideB,
    const float* __restrict__ bias,
    float* __restrict__ Cf, long strideC,
    __hip_bfloat16* __restrict__ Cb, long strideCb,
    __hip_bfloat16* __restrict__ Cb2, long strideCb2,
    int M, int N, int K)
{
  __shared__ short8 sA[128][8];   // 16KB
  __shared__ short8 sB[128][8];   // 16KB
  int tid = threadIdx.x;
  int lane = tid & 63;
  int w = tid >> 6;
  int wm = w >> 1, wn = w & 1;
  int r15 = lane & 15, koct = lane >> 4;

  int gx = gridDim.x;
  int nwg = gx * gridDim.y;
  int bid = blockIdx.y * gx + blockIdx.x;
  int bx, by;
  if (gridDim.y == 64 && (nwg & 7) == 0) {
    int xcd = bid & 7, c = bid >> 3;
    by = xcd*8 + (c & 7);
    bx = c >> 3;
  } else {
    bx = blockIdx.x; by = blockIdx.y;
  }
  int m0 = by * 128, n0 = bx * 128;

  const short* aSrc[4]; const short* bSrc[4];
  {
    int row = w*32 + (lane >> 3);
    int slot = lane & 7;
    #pragma unroll
    for (int c = 0; c < 4; ++c) {
      int r = row + c*8;
      int ga = m0 + r; if (ga > M-1) ga = M-1;
      int gb = n0 + r;
      int sw = slot ^ (r & 7);
      aSrc[c] = A  + (size_t)ga*strideA + sw*8;
      bSrc[c] = Bt + (size_t)gb*strideB + sw*8;
    }
  }

  f32x4 acc[4][4] = {};
  for (int k0 = 0; k0 < K; k0 += 64) {
    #pragma unroll
    for (int c = 0; c < 4; ++c) {
      gload16(aSrc[c] + k0, (short8*)sA + (w*4 + c)*64);
      gload16(bSrc[c] + k0, (short8*)sB + (w*4 + c)*64);
    }
    __syncthreads();
    #pragma unroll
    for (int ks = 0; ks < 2; ++ks) {
      short8 a[4], b[4];
      #pragma unroll
      for (int mf = 0; mf < 4; ++mf) {
        int lr = wm*64 + mf*16 + r15;
        a[mf] = sA[lr][(ks*4 + koct) ^ (lr & 7)];
      }
      #pragma unroll
      for (int nf = 0; nf < 4; ++nf) {
        int lr = wn*64 + nf*16 + r15;
        b[nf] = sB[lr][(ks*4 + koct) ^ (lr & 7)];
      }
      #pragma unroll
      for (int mf = 0; mf < 4; ++mf)
        #pragma unroll
        for (int nf = 0; nf < 4; ++nf)
          acc[mf][nf] = __builtin_amdgcn_mfma_f32_16x16x32_bf16(a[mf], b[nf], acc[mf][nf], 0, 0, 0);
    }
    __syncthreads();
  }
  #pragma unroll
  for (int mf = 0; mf < 4; ++mf) {
    #pragma unroll
    for (int r = 0; r < 4; ++r) {
      int grow = m0 + wm*64 + mf*16 + koct*4 + r;
      if (grow >= M) continue;
      #pragma unroll
      for (int nf = 0; nf < 4; ++nf) {
        int gcol = n0 + wn*64 + nf*16 + r15;
        if (gcol >= N) continue;
        float v = acc[mf][nf][r] + bias[gcol];
        if (EPI == 0) {
          __builtin_nontemporal_store(fast_softplus(v), &Cf[(size_t)grow*strideC + gcol]);
        } else {
          __hip_bfloat16 hb = __float2bfloat16(v);
          Cb[(size_t)grow*strideCb + gcol] = hb;
          if (Cb2) Cb2[(size_t)grow*strideCb2 + gcol] = hb;
        }
      }
    }
  }
}

// ---------------- W[k][n] f32 -> Wt[n][k] bf16 (strided rows) -------------
__global__ __launch_bounds__(256) void k_transpose_bf16(
    const float* __restrict__ W, int ldw,
    __hip_bfloat16* __restrict__ Wt, long strideT)
{
  __shared__ float s[64][65];
  int n0 = blockIdx.x * 64, k0 = blockIdx.y * 64;
  int tid = threadIdx.x;
  for (int p = 0; p < 16; ++p) {
    int idx = p*256 + tid;
    int kk = idx >> 6, nn = idx & 63;
    s[kk][nn] = W[(size_t)(k0+kk)*ldw + n0 + nn];
  }
  __syncthreads();
  for (int p = 0; p < 16; ++p) {
    int idx = p*256 + tid;
    int nn = idx >> 6, kk = idx & 63;
    Wt[(size_t)(n0+nn)*strideT + k0 + kk] = __float2bfloat16(s[kk][nn]);
  }
}

// ---------------- merged-A f32 -> bf16 copy (cols 1536..2624 -> BCOL_MGA) --
__global__ __launch_bounds__(256) void k_castA(float* __restrict__ out)
{
  int r = blockIdx.x;
  int tid = threadIdx.x;
  const float* src = out + (size_t)r*RS + COL_FF;
  short* dst = (short*)out + (size_t)r*RS2 + BCOL_MGA;
  for (int i = tid; i < 1088; i += 256)
    dst[i] = bf16b(src[i]);
}

// ---------------- K/V f32 -> bf16 ws buffers (V transposed) ---------------
__global__ __launch_bounds__(256) void k_kvcast(
    const float* __restrict__ out, short* __restrict__ Kb, short* __restrict__ Vt)
{
  __shared__ float sV[32][65];
  int tt = blockIdx.x, bh = blockIdx.y;
  int b = bh >> 2, h = bh & 3;
  int tid = threadIdx.x;
  #pragma unroll
  for (int i = 0; i < 8; ++i) {
    int idx = i*256 + tid;
    int tp = idx >> 6, d = idx & 63;
    int t = tt*32 + tp;
    float vv = 0.f;
    if (t < LH) {
      const float* row = out + (size_t)(b*LH + t)*RS;
      Kb[((size_t)bh*511 + t)*64 + d] = bf16b(row[COL_K + h*64 + d]);
      vv = row[COL_V + h*64 + d];
    }
    sV[tp][d] = vv;
  }
  __syncthreads();
  #pragma unroll
  for (int i = 0; i < 8; ++i) {
    int idx = i*256 + tid;
    int d = idx >> 5, tp = idx & 31;
    Vt[((size_t)bh*64 + d)*512 + tt*32 + tp] = bf16b(sV[tp][d]);
  }
}

// ---------------- flash-MFMA attention v1 (fallback, f32 K/V) -------------
__global__ __launch_bounds__(64) void k_attn_mfma(float* __restrict__ out)
{
  int qt = blockIdx.x, h = blockIdx.y, b = blockIdx.z;
  int lane = threadIdx.x & 63;
  int r15 = lane & 15, koct = lane >> 4;
  __shared__ short Vt[64][40];
  __shared__ short Pl[16][40];
  const float* base = out + (size_t)b*LH*RS;

  int qrow = qt*16 + r15; if (qrow > LH-1) qrow = LH-1;
  const float* qp = base + (size_t)qrow*RS + COL_Q + h*64 + koct*8;
  short8 qf[2];
  #pragma unroll
  for (int d2 = 0; d2 < 2; ++d2) {
    f32x4 lo = *(const f32x4*)(qp + d2*32);
    f32x4 hi = *(const f32x4*)(qp + d2*32 + 4);
    short8 t;
    #pragma unroll
    for (int i = 0; i < 4; ++i) { t[i] = bf16b(lo[i]); t[i+4] = bf16b(hi[i]); }
    qf[d2] = t;
  }

  f32x4 o[4] = {};
  float m = -3.0e38f, l = 0.f;
  int qg = qt*16 + r15;
  int nt = qt/2 + 1;

  for (int ti = 0; ti < nt; ++ti) {
    int kv0 = ti*32;
    __syncthreads();
    {
      const float* vbase = base + COL_V + h*64 + lane;
      #pragma unroll 4
      for (int j = 0; j < 32; ++j) {
        int kvr = kv0 + j; if (kvr > LH-1) kvr = LH-1;
        Vt[lane][j] = bf16b(vbase[(size_t)kvr*RS]);
      }
    }
    f32x4 s[2] = {};
    #pragma unroll
    for (int kvf = 0; kvf < 2; ++kvf) {
      int kvr = kv0 + kvf*16 + r15; if (kvr > LH-1) kvr = LH-1;
      const float* kp = base + (size_t)kvr*RS + COL_K + h*64 + koct*8;
      #pragma unroll
      for (int d2 = 0; d2 < 2; ++d2) {
        f32x4 lo = *(const f32x4*)(kp + d2*32);
        f32x4 hi = *(const f32x4*)(kp + d2*32 + 4);
        short8 t;
        #pragma unroll
        for (int i = 0; i < 4; ++i) { t[i] = bf16b(lo[i]); t[i+4] = bf16b(hi[i]); }
        s[kvf] = __builtin_amdgcn_mfma_f32_16x16x32_bf16(t, qf[d2], s[kvf], 0, 0, 0);
      }
    }
    float sv[2][4];
    float mx = -3.0e38f;
    #pragma unroll
    for (int kvf = 0; kvf < 2; ++kvf)
      #pragma unroll
      for (int r = 0; r < 4; ++r) {
        int kvg = kv0 + kvf*16 + koct*4 + r;
        float x = s[kvf][r] * 0.125f;
        if (kvg > qg) x = -3.0e38f;
        sv[kvf][r] = x;
        mx = fmaxf(mx, x);
      }
    mx = fmaxf(mx, __shfl_xor(mx, 16));
    mx = fmaxf(mx, __shfl_xor(mx, 32));
    float mn = fmaxf(m, mx);
    float alpha = expf(m - mn);
    m = mn;
    float ls = 0.f;
    sshort4 pk[2];
    #pragma unroll
    for (int kvf = 0; kvf < 2; ++kvf)
      #pragma unroll
      for (int r = 0; r < 4; ++r) {
        float p = expf(sv[kvf][r] - mn);
        ls += p;
        pk[kvf][r] = bf16b(p);
      }
    l = l*alpha + ls;
    *(sshort4*)&Pl[r15][koct*4]      = pk[0];
    *(sshort4*)&Pl[r15][16 + koct*4] = pk[1];
    __syncthreads();
    float arr[4];
    #pragma unroll
    for (int r = 0; r < 4; ++r) arr[r] = __shfl(alpha, koct*4 + r);
    #pragma unroll
    for (int df = 0; df < 4; ++df)
      #pragma unroll
      for (int r = 0; r < 4; ++r) o[df][r] *= arr[r];
    short8 pa = *(const short8*)&Pl[r15][koct*8];
    #pragma unroll
    for (int df = 0; df < 4; ++df) {
      short8 vb = *(const short8*)&Vt[df*16 + r15][koct*8];
      o[df] = __builtin_amdgcn_mfma_f32_16x16x32_bf16(pa, vb, o[df], 0, 0, 0);
    }
  }
  l += __shfl_xor(l, 16);
  l += __shfl_xor(l, 32);
  float linv = 1.f / l;
  float lr[4];
  #pragma unroll
  for (int r = 0; r < 4; ++r) lr[r] = __shfl(linv, koct*4 + r);
  #pragma unroll
  for (int df = 0; df < 4; ++df)
    #pragma unroll
    for (int r = 0; r < 4; ++r) {
      int qq = qt*16 + koct*4 + r;
      if (qq < LH)
        out[((size_t)(b*LH + qq))*RS + COL_ATTN + h*64 + df*16 + r15] = o[df][r] * lr[r];
    }
}

// ---------------- flash-MFMA attention v2 (bf16 K/Vt in ws) ---------------
__global__ __launch_bounds__(64) void k_attn_mfma2(
    const short* __restrict__ Kb, const short* __restrict__ Vt,
    float* __restrict__ out)
{
  int qt = blockIdx.x, h = blockIdx.y, b = blockIdx.z;
  int lane = threadIdx.x & 63;
  int r15 = lane & 15, koct = lane >> 4;
  __shared__ short Pl[16][40];
  int bh = b*4 + h;
  const short* Kbh = Kb + (size_t)bh*511*64;
  const short* Vbh = Vt + (size_t)bh*64*512;
  const float* base = out + (size_t)b*LH*RS;

  int qrow = qt*16 + r15; if (qrow > LH-1) qrow = LH-1;
  const float* qp = base + (size_t)qrow*RS + COL_Q + h*64 + koct*8;
  short8 qf[2];
  #pragma unroll
  for (int d2 = 0; d2 < 2; ++d2) {
    f32x4 lo = *(const f32x4*)(qp + d2*32);
    f32x4 hi = *(const f32x4*)(qp + d2*32 + 4);
    short8 t;
    #pragma unroll
    for (int i = 0; i < 4; ++i) { t[i] = bf16b(lo[i]); t[i+4] = bf16b(hi[i]); }
    qf[d2] = t;
  }

  f32x4 o[4] = {};
  float m = -3.0e38f, l = 0.f;
  int qg = qt*16 + r15;
  int nt = qt/2 + 1;

  for (int ti = 0; ti < nt; ++ti) {
    int kv0 = ti*32;
    f32x4 s[2] = {};
    #pragma unroll
    for (int kvf = 0; kvf < 2; ++kvf) {
      int kvr = kv0 + kvf*16 + r15; if (kvr > LH-1) kvr = LH-1;
      const short* kp = Kbh + (size_t)kvr*64 + koct*8;
      short8 ka0 = *(const short8*)kp;
      short8 ka1 = *(const short8*)(kp + 32);
      s[kvf] = __builtin_amdgcn_mfma_f32_16x16x32_bf16(ka0, qf[0], s[kvf], 0, 0, 0);
      s[kvf] = __builtin_amdgcn_mfma_f32_16x16x32_bf16(ka1, qf[1], s[kvf], 0, 0, 0);
    }
    float sv[2][4];
    float mx = -3.0e38f;
    #pragma unroll
    for (int kvf = 0; kvf < 2; ++kvf)
      #pragma unroll
      for (int r = 0; r < 4; ++r) {
        int kvg = kv0 + kvf*16 + koct*4 + r;
        float x = s[kvf][r] * 0.125f;
        if (kvg > qg) x = -3.0e38f;
        sv[kvf][r] = x;
        mx = fmaxf(mx, x);
      }
    mx = fmaxf(mx, __shfl_xor(mx, 16));
    mx = fmaxf(mx, __shfl_xor(mx, 32));
    float mn = fmaxf(m, mx);
    float alpha = expf(m - mn);
    m = mn;
    float ls = 0.f;
    sshort4 pk[2];
    #pragma unroll
    for (int kvf = 0; kvf < 2; ++kvf)
      #pragma unroll
      for (int r = 0; r < 4; ++r) {
        float p = expf(sv[kvf][r] - mn);
        ls += p;
        pk[kvf][r] = bf16b(p);
      }
    l = l*alpha + ls;
    *(sshort4*)&Pl[r15][koct*4]      = pk[0];
    *(sshort4*)&Pl[r15][16 + koct*4] = pk[1];
    __syncthreads();   // 1-wave barrier: orders P write->read (cheap)
    float arr[4];
    #pragma unroll
    for (int r = 0; r < 4; ++r) arr[r] = __shfl(alpha, koct*4 + r);
    #pragma unroll
    for (int df = 0; df < 4; ++df)
      #pragma unroll
      for (int r = 0; r < 4; ++r) o[df][r] *= arr[r];
    short8 pa = *(const short8*)&Pl[r15][koct*8];
    #pragma unroll
    for (int df = 0; df < 4; ++df) {
      short8 vb = *(const short8*)(Vbh + (size_t)(df*16 + r15)*512 + kv0 + koct*8);
      o[df] = __builtin_amdgcn_mfma_f32_16x16x32_bf16(pa, vb, o[df], 0, 0, 0);
    }
  }
  l += __shfl_xor(l, 16);
  l += __shfl_xor(l, 32);
  float linv = 1.f / l;
  float lr[4];
  #pragma unroll
  for (int r = 0; r < 4; ++r) lr[r] = __shfl(linv, koct*4 + r);
  #pragma unroll
  for (int df = 0; df < 4; ++df)
    #pragma unroll
    for (int r = 0; r < 4; ++r) {
      int qq = qt*16 + koct*4 + r;
      if (qq < LH)
        out[((size_t)(b*LH + qq))*RS + COL_ATTN + h*64 + df*16 + r15] = o[df][r] * lr[r];
    }
}

// ---------------- flatF[:,512:768]=sub_embed, [:,768:1024]=rel_embed ------
__global__ __launch_bounds__(256) void k_feats(
    const int* __restrict__ subs, const int* __restrict__ marks,
    const float* __restrict__ sub_embed, const float* __restrict__ rel_embed,
    float* __restrict__ out)
{
  int bt = blockIdx.x;
  int b = bt / LH;
  int d = threadIdx.x;
  out[(size_t)bt*RS + COL_FF + 512 + d] = sub_embed[(size_t)subs[b*L_]*256 + d];
  out[(size_t)bt*RS + COL_FF + 768 + d] = rel_embed[(size_t)marks[b*L_]*256 + d];
}

// ---------------- zero gsum / gcnt ----------------------------------------
__global__ __launch_bounds__(256) void k_zero(float* __restrict__ out)
{
  int s = blockIdx.x;  // 0..1023
  for (int c = threadIdx.x; c < DFEAT; c += 256)
    out[(size_t)s*RS + COL_GSUM + c] = 0.f;
  if (threadIdx.x == 0) out[(size_t)s*RS + COL_GCNT] = 0.f;
}

// ---------------- masked segment sum (atomics) ----------------------------
__global__ __launch_bounds__(256) void k_segsum(
    const int* __restrict__ subs, const int* __restrict__ marks,
    const void* __restrict__ mask,
    const int* __restrict__ group_map, float* __restrict__ out)
{
  int bt = blockIdx.x;
  int b = bt / LH, t = bt - b*LH;
  int boolmode = ((const int*)out)[COL_FLAG];
  if (!mask_at(mask, b*L_ + t, boolmode)) return;
  int gid = group_map[subs[b*L_+t]*NRELS + marks[b*L_+t]];
  int key = b*NG + gid;
  const float* src = out + (size_t)bt*RS + COL_FF;
  float* dst = out + (size_t)key*RS + COL_GSUM;
  for (int d = threadIdx.x; d < DFEAT; d += 256)
    atomicAdd(&dst[d], src[d]);
  if (threadIdx.x == 0) atomicAdd(&out[(size_t)key*RS + COL_GCNT], 1.0f);
}

// ---------------- gp = (gsum/cnt) @ gp_w + gp_b ---------------------------
__global__ __launch_bounds__(64) void k_gp(
    const float* __restrict__ gp_w, const float* __restrict__ gp_b,
    float* __restrict__ out)
{
  int s = blockIdx.x;
  int j = threadIdx.x;
  float inv = 1.0f / fmaxf(out[(size_t)s*RS + COL_GCNT], 1.0f);
  float acc = 0.f;
  const float* gs = out + (size_t)s*RS + COL_GSUM;
  for (int k2 = 0; k2 < DFEAT; ++k2)
    acc += gs[k2] * gp_w[k2*GPDIM + j];
  out[(size_t)s*RS + COL_GP + j] = acc * inv + gp_b[j];
}

// ---------------- whole group transformer per batch, all in LDS -----------
__global__ __launch_bounds__(256) void k_group(
    const float* __restrict__ ga_in_w, const float* __restrict__ ga_in_b,
    const float* __restrict__ ga_out_w, const float* __restrict__ ga_out_b,
    const float* __restrict__ ffn_w1, const float* __restrict__ ffn_b1,
    const float* __restrict__ ffn_w2, const float* __restrict__ ffn_b2,
    const float* __restrict__ n1_w, const float* __restrict__ n1_b,
    const float* __restrict__ n2_w, const float* __restrict__ n2_b,
    float* __restrict__ out)
{
  __shared__ float sGP[64][64];
  __shared__ float sQ[64][64];
  __shared__ float sK[64][64];
  __shared__ float sV[64][64];
  int b = blockIdx.x, tid = threadIdx.x;
  for (int i = tid; i < 4096; i += 256)
    sGP[i>>6][i&63] = out[(size_t)(b*64 + (i>>6))*RS + COL_GP + (i&63)];
  __syncthreads();
  for (int i = tid; i < 64*192; i += 256) {
    int g = i / 192, c = i - g*192;
    float acc = ga_in_b[c];
    for (int k2 = 0; k2 < 64; ++k2) acc += sGP[g][k2] * ga_in_w[k2*192 + c];
    if (c < 64)       sQ[g][c]      = acc;
    else if (c < 128) sK[g][c-64]   = acc;
    else              sV[g][c-128]  = acc;
  }
  __syncthreads();
  if (tid < 128) {
    int qi = tid >> 1, h = tid & 1, base = h*32;
    float sc[64];
    float mx = -3.0e38f;
    #pragma unroll
    for (int k2 = 0; k2 < 64; ++k2) {
      float d2 = 0.f;
      #pragma unroll
      for (int d = 0; d < 32; ++d) d2 += sQ[qi][base+d] * sK[k2][base+d];
      d2 *= 0.17677669529663689f;
      sc[k2] = d2;
      mx = fmaxf(mx, d2);
    }
    float den = 0.f;
    #pragma unroll
    for (int k2 = 0; k2 < 64; ++k2) { sc[k2] = expf(sc[k2]-mx); den += sc[k2]; }
    float inv = 1.f/den;
    #pragma unroll
    for (int d = 0; d < 32; ++d) {
      float acc = 0.f;
      #pragma unroll
      for (int k2 = 0; k2 < 64; ++k2) acc += sc[k2] * sV[k2][base+d];
      sQ[qi][base+d] = acc * inv;
    }
  }
  __syncthreads();
  for (int i = tid; i < 4096; i += 256) {
    int g = i>>6, c = i&63;
    float acc = ga_out_b[c];
    for (int k2 = 0; k2 < 64; ++k2) acc += sQ[g][k2] * ga_out_w[k2*64 + c];
    sK[g][c] = sGP[g][c] + acc;
  }
  __syncthreads();
  if (tid < 64) {
    int g = tid;
    float mu = 0.f; for (int c=0;c<64;c++) mu += sK[g][c]; mu *= (1.f/64.f);
    float var = 0.f; for (int c=0;c<64;c++){float d2=sK[g][c]-mu; var += d2*d2;} var *= (1.f/64.f);
    float inv = 1.0f / sqrtf(var + 1e-5f);
    for (int c=0;c<64;c++) sK[g][c] = (sK[g][c]-mu)*inv*n1_w[c] + n1_b[c];
  }
  __syncthreads();
  for (int i = tid; i < 4096; i += 256) {
    int g = i>>6, c = i&63;
    float acc = ffn_b1[c];
    for (int k2 = 0; k2 < 64; ++k2) acc += sK[g][k2] * ffn_w1[k2*64 + c];
    sV[g][c] = fmaxf(acc, 0.f);
  }
  __syncthreads();
  for (int i = tid; i < 4096; i += 256) {
    int g = i>>6, c = i&63;
    float acc = ffn_b2[c];
    for (int k2 = 0; k2 < 64; ++k2) acc += sV[g][k2] * ffn_w2[k2*64 + c];
    sGP[g][c] = sK[g][c] + acc;
  }
  __syncthreads();
  if (tid < 64) {
    int g = tid;
    float mu = 0.f; for (int c=0;c<64;c++) mu += sGP[g][c]; mu *= (1.f/64.f);
    float var = 0.f; for (int c=0;c<64;c++){float d2=sGP[g][c]-mu; var += d2*d2;} var *= (1.f/64.f);
    float inv = 1.0f / sqrtf(var + 1e-5f);
    for (int c=0;c<64;c++)
      out[(size_t)(b*64 + g)*RS + COL_GOUT + c] = (sGP[g][c]-mu)*inv*n2_w[c] + n2_b[c];
  }
}

// ---------------- gathered = gout[keys] * fm ------------------------------
__global__ __launch_bounds__(64) void k_gather(
    const int* __restrict__ subs, const int* __restrict__ marks,
    const void* __restrict__ mask,
    const int* __restrict__ group_map, float* __restrict__ out)
{
  int bt = blockIdx.x;
  int b = bt / LH, t = bt - b*LH;
  int j = threadIdx.x;
  int boolmode = ((const int*)out)[COL_FLAG];
  float val = 0.f;
  if (mask_at(mask, b*L_ + t, boolmode)) {
    int gid = group_map[subs[b*L_+t]*NRELS + marks[b*L_+t]];
    val = out[(size_t)(b*NG + gid)*RS + COL_GOUT + j];
  }
  out[(size_t)bt*RS + COL_GATH + j] = val;
}

// ---------------- tail v6 (fallback when ws too small) --------------------
__global__ __launch_bounds__(256) void k_tail_v6(
    const float* __restrict__ int_w, const float* __restrict__ int_b,
    float* __restrict__ out)
{
  __shared__ short8 sA[16][128];
  __shared__ short8 sB[2][128][8];
  int m0 = blockIdx.x * 16;
  int tid = threadIdx.x;
  int lane = tid & 63;
  int w = tid >> 6;
  int r15 = lane & 15, koct = lane >> 4;
  const short* eb = (const short*)out + BCOL_ENH;

  for (int idx = tid; idx < 16*128; idx += 256) {
    int r = idx >> 7, c8 = idx & 127;
    int row = m0 + r; if (row > RTOT-1) row = RTOT-1;
    sA[r][c8 ^ (r & 7)] = *(const short8*)(eb + (size_t)row*RS2 + c8*8);
  }

  int tn2 = tid & 63;
  int tk4 = tid >> 6;
  int xA = r15 & 7;

  f32x2 v[16];
  auto issueB = [&](int s) {
    int ntile = s >> 4, ks = s & 15;
    int nb = N1 + ntile*128 + tn2*2;
    int ncl = nb <= NENT-2 ? nb : NENT-2;
    const float* bp = int_w + (size_t)(ks*64 + tk4*16)*NENT + ncl;
    #pragma unroll
    for (int i = 0; i < 16; ++i) v[i] = *(const f32x2*)(bp + (size_t)i*NENT);
  };

  issueB(0);
  __syncthreads();

  f32x4 acc[2] = {};
  for (int s = 0; s < 144; ++s) {
    int ks = s & 15;
    int buf = s & 1;
    {
      short h0[16], h1[16];
      #pragma unroll
      for (int i = 0; i < 16; ++i) { h0[i] = bf16b(v[i][0]); h1[i] = bf16b(v[i][1]); }
      short8 p0lo, p0hi, p1lo, p1hi;
      #pragma unroll
      for (int i = 0; i < 8; ++i) {
        p0lo[i] = h0[i]; p0hi[i] = h0[i+8];
        p1lo[i] = h1[i]; p1hi[i] = h1[i+8];
      }
      int nl0 = tn2*2, nl1 = tn2*2 + 1;
      sB[buf][nl0][(tk4*2 + 0) ^ (nl0 & 7)] = p0lo;
      sB[buf][nl0][(tk4*2 + 1) ^ (nl0 & 7)] = p0hi;
      sB[buf][nl1][(tk4*2 + 0) ^ (nl1 & 7)] = p1lo;
      sB[buf][nl1][(tk4*2 + 1) ^ (nl1 & 7)] = p1hi;
    }
    if (s + 1 < 144) issueB(s + 1);
    __syncthreads();
    #pragma unroll
    for (int ksub = 0; ksub < 2; ++ksub) {
      int c8A = ks*8 + ksub*4 + koct;
      short8 a0 = sA[r15][c8A ^ xA];
      #pragma unroll
      for (int nf = 0; nf < 2; ++nf) {
        int nloc = w*32 + nf*16 + r15;
        short8 b = sB[buf][nloc][(ksub*4 + koct) ^ (nloc & 7)];
        acc[nf] = __builtin_amdgcn_mfma_f32_16x16x32_bf16(a0, b, acc[nf], 0, 0, 0);
      }
    }
    if (ks == 15) {
      int n0 = N1 + (s >> 4)*128;
      #pragma unroll
      for (int nf = 0; nf < 2; ++nf) {
        int n = n0 + w*32 + nf*16 + r15;
        if (n < NENT) {
          float bv = int_b[n];
          #pragma unroll
          for (int r = 0; r < 4; ++r) {
            int g = m0 + koct*4 + r;
            if (g < RTOT)
              __builtin_nontemporal_store(fast_softplus(acc[nf][r] + bv),
                                          &out[(size_t)g*RS + n]);
          }
        }
        acc[nf] = (f32x4){0.f, 0.f, 0.f, 0.f};
      }
    }
  }
}

// ---------------- tail v8: B pre-transposed bf16 in d_ws ------------------
__global__ __launch_bounds__(256) void k_tail_v8(
    const short* __restrict__ Bt, const float* __restrict__ int_b,
    float* __restrict__ out)
{
  __shared__ short8 sA[16][128];
  __shared__ short8 sB[2][128][8];
  int m0 = blockIdx.x * 16;
  int tid = threadIdx.x;
  int lane = tid & 63;
  int w = tid >> 6;
  int r15 = lane & 15, koct = lane >> 4;
  const short* eb = (const short*)out + BCOL_ENH;

  for (int idx = tid; idx < 16*128; idx += 256) {
    int r = idx >> 7, c8 = idx & 127;
    int row = m0 + r; if (row > RTOT-1) row = RTOT-1;
    sA[r][c8 ^ (r & 7)] = *(const short8*)(eb + (size_t)row*RS2 + c8*8);
  }

  int rl8 = w*8 + (lane >> 3);
  int slot = lane & 7;
  int xA = r15 & 7;

  auto issueB = [&](int s) {
    int ntile = s >> 4, ks = s & 15;
    #pragma unroll
    for (int c = 0; c < 4; ++c) {
      int rowL = c*32 + rl8;
      int wsrow = ntile*128 + rowL;
      if (wsrow > 1087) wsrow = 1087;
      int sw = slot ^ (rowL & 7);
      gload16(Bt + (size_t)wsrow*1024 + ks*64 + sw*8,
              (short8*)&sB[s & 1][c*32 + w*8][0]);
    }
  };

  issueB(0);
  __syncthreads();

  f32x4 acc[2] = {};
  for (int s = 0; s < 144; ++s) {
    int ks = s & 15, buf = s & 1;
    if (s + 1 < 144) issueB(s + 1);
    #pragma unroll
    for (int ksub = 0; ksub < 2; ++ksub) {
      int c8A = ks*8 + ksub*4 + koct;
      short8 a0 = sA[r15][c8A ^ xA];
      #pragma unroll
      for (int nf = 0; nf < 2; ++nf) {
        int nloc = w*32 + nf*16 + r15;
        short8 b = sB[buf][nloc][(ksub*4 + koct) ^ (nloc & 7)];
        acc[nf] = __builtin_amdgcn_mfma_f32_16x16x32_bf16(a0, b, acc[nf], 0, 0, 0);
      }
    }
    if (ks == 15) {
      int n0 = N1 + (s >> 4)*128;
      #pragma unroll
      for (int nf = 0; nf < 2; ++nf) {
        int n = n0 + w*32 + nf*16 + r15;
        if (n < NENT) {
          float bv = int_b[n];
          #pragma unroll
          for (int r = 0; r < 4; ++r) {
            int g = m0 + koct*4 + r;
            if (g < RTOT)
              __builtin_nontemporal_store(fast_softplus(acc[nf][r] + bv),
                                          &out[(size_t)g*RS + n]);
          }
        }
        acc[nf] = (f32x4){0.f, 0.f, 0.f, 0.f};
      }
    }
    __syncthreads();
  }
}

extern "C" void kernel_launch(void* const* d_in, const int* in_sizes, int n_in,
                              void* d_out, int out_size, void* d_ws, size_t ws_size,
                              hipStream_t stream)
{
  const int*   subs      = (const int*)  d_in[0];
  const int*   marks     = (const int*)  d_in[1];
  const int*   objs      = (const int*)  d_in[2];
  const float* times     = (const float*)d_in[3];
  const float* dts       = (const float*)d_in[4];
  const void*  mask      =               d_in[5];
  const int*   group_map = (const int*)  d_in[6];
  const float* obj_embed = (const float*)d_in[7];
  const float* Wq        = (const float*)d_in[8];
  const float* Wk        = (const float*)d_in[9];
  const float* Wv        = (const float*)d_in[10];
  const float* Wo        = (const float*)d_in[11];
  const float* sub_embed = (const float*)d_in[12];
  const float* rel_embed = (const float*)d_in[13];
  const float* gp_w      = (const float*)d_in[14];
  const float* gp_b      = (const float*)d_in[15];
  const float* ga_in_w   = (const float*)d_in[16];
  const float* ga_in_b   = (const float*)d_in[17];
  const float* ga_out_w  = (const float*)d_in[18];
  const float* ga_out_b  = (const float*)d_in[19];
  const float* ffn_w1    = (const float*)d_in[20];
  const float* ffn_b1    = (const float*)d_in[21];
  const float* ffn_w2    = (const float*)d_in[22];
  const float* ffn_b2    = (const float*)d_in[23];
  const float* n1_w      = (const float*)d_in[24];
  const float* n1_b      = (const float*)d_in[25];
  const float* n2_w      = (const float*)d_in[26];
  const float* n2_b      = (const float*)d_in[27];
  const float* mg_w      = (const float*)d_in[28];
  const float* mg_b      = (const float*)d_in[29];
  const float* int_w     = (const float*)d_in[30];
  const float* int_b     = (const float*)d_in[31];
  float* out = (float*)d_out;
  __hip_bfloat16* ob = (__hip_bfloat16*)d_out;

  bool ws_ok  = ws_size >= (size_t)1088 * 1024 * sizeof(__hip_bfloat16);
  bool ws_ok2 = ws_size >= WS_NEED2;
  bool ws_ok3 = ws_size >= WS_NEED3;

  short* wsK = ws_ok3 ? (short*)((char*)d_ws + WS2_K) : (short*)((char*)d_ws + WS_OFF_K);
  short* wsV = ws_ok3 ? (short*)((char*)d_ws + WS2_V) : (short*)((char*)d_ws + WS_OFF_V);
  __hip_bfloat16* wsENH = (__hip_bfloat16*)((char*)d_ws + WS2_ENH);

  k_detect<<<1, 256, 0, stream>>>((const unsigned int*)mask, out);
  k_transpose_bf16<<<dim3(N1/64, DFEAT/64), 256, 0, stream>>>(int_w, NENT, ob + BCOL_WT, RS2);
  k_transpose_bf16<<<dim3(DFEAT/64, 1088/64), 256, 0, stream>>>(mg_w, DFEAT, ob + BCOL_MGWT, RS2);
  if (ws_ok) {
    // tail Bt: int_w cols [6912, 8000) -> ws rows 0..1087, stride 1024
    k_transpose_bf16<<<dim3(1088/64, DFEAT/64), 256, 0, stream>>>(
        int_w + N1, NENT, (__hip_bfloat16*)d_ws, 1024);
  }
  for (int l = 0; l < 2; ++l) {
    const float* ws[4] = { Wq + (size_t)l*DM*DM, Wk + (size_t)l*DM*DM,
                           Wv + (size_t)l*DM*DM, Wo + (size_t)l*DM*DM };
    for (int j = 0; j < 4; ++j)
      k_transpose_bf16<<<dim3(4, 4), 256, 0, stream>>>(
          ws[j], DM, ob + BCOL_ENCW + (size_t)((l*4 + j)*256)*RS2, RS2);
  }

  k_build_x_cur<<<RTOT, 256, 0, stream>>>(objs, times, dts, obj_embed, out);

  for (int l = 0; l < 2; ++l) {
    const short* encw = (const short*)(ob + BCOL_ENCW);
    const short* wtq = encw + (size_t)((l*4 + 0)*256)*RS2;
    const short* wtk = encw + (size_t)((l*4 + 1)*256)*RS2;
    const short* wto = encw + (size_t)((l*4 + 3)*256)*RS2;
    gemm_mfma<true, 3><<<dim3(2, 64), 256, 0, stream>>>(
        out + COL_CUR, RS, wtq, RS2, nullptr,
        out + COL_Q, RS, nullptr, 0, nullptr, 0, 0, RTOT, DM);
    gemm_mfma<true, 3><<<dim3(4, 64), 256, 0, stream>>>(
        out + COL_X, RS, wtk, RS2, nullptr,
        out + COL_K, RS, nullptr, 0, nullptr, 0, 0, RTOT, DM);
    if (ws_ok2) {
      k_kvcast<<<dim3(16, 64), 256, 0, stream>>>(out, wsK, wsV);
      k_attn_mfma2<<<dim3(32, 4, B_), 64, 0, stream>>>(wsK, wsV, out);
    } else {
      k_attn_mfma<<<dim3(32, 4, B_), 64, 0, stream>>>(out);
    }
    gemm_mfma<true, 2><<<dim3(2, 64), 256, 0, stream>>>(
        out + COL_ATTN, RS, wto, RS2, nullptr,
        out + COL_CUR, RS, nullptr, 0, out + COL_FF, RS, l*DM, RTOT, DM);
  }

  k_feats<<<RTOT, 256, 0, stream>>>(subs, marks, sub_embed, rel_embed, out);
  k_zero<<<1024, 256, 0, stream>>>(out);
  k_segsum<<<RTOT, 256, 0, stream>>>(subs, marks, mask, group_map, out);
  k_gp<<<1024, 64, 0, stream>>>(gp_w, gp_b, out);
  k_group<<<B_, 256, 0, stream>>>(ga_in_w, ga_in_b, ga_out_w, ga_out_b,
                                  ffn_w1, ffn_b1, ffn_w2, ffn_b2,
                                  n1_w, n1_b, n2_w, n2_b, out);
  k_gather<<<RTOT, 64, 0, stream>>>(subs, marks, mask, group_map, out);

  // cast merged A (flatF|gath) to bf16 at BCOL_MGA, then merge via LDS GEMM.
  // ws_ok3: ENH lives ONLY in ws (dense 16.7MB buffer); d_out ENH never
  // written (tail overwrites those output cols anyway).
  k_castA<<<RTOT, 256, 0, stream>>>(out);
  if (ws_ok3) {
    gemm_mfma_lds<1><<<dim3(DFEAT/128, 64), 256, 0, stream>>>(
        (const short*)(ob + BCOL_MGA), RS2, (const short*)(ob + BCOL_MGWT), RS2, mg_b,
        nullptr, 0, wsENH, 1024, nullptr, 0, RTOT, DFEAT, 1088);
    // F1: A = dense ws ENH copy
    gemm_mfma_lds<0><<<dim3(N1/128, (RTOT+127)/128), 256, 0, stream>>>(
        (const short*)wsENH, 1024, (const short*)(ob + BCOL_WT), RS2, int_b,
        out, RS, nullptr, 0, nullptr, 0, RTOT, N1, DFEAT);
    // tail: A = ws ENH, B = ws Bt (padded rows), N-guard 1088
    gemm_mfma_lds<0><<<dim3(9, 64), 256, 0, stream>>>(
        (const short*)wsENH, 1024, (const short*)d_ws, 1024, int_b + N1,
        out + N1, RS, nullptr, 0, nullptr, 0, RTOT, 1088, DFEAT);
  } else {
    gemm_mfma_lds<1><<<dim3(DFEAT/128, 64), 256, 0, stream>>>(
        (const short*)(ob + BCOL_MGA), RS2, (const short*)(ob + BCOL_MGWT), RS2, mg_b,
        nullptr, 0, ob + BCOL_ENH, RS2, nullptr, 0, RTOT, DFEAT, 1088);
    gemm_mfma_lds<0><<<dim3(N1/128, (RTOT+127)/128), 256, 0, stream>>>(
        (const short*)(ob + BCOL_ENH), RS2, (const short*)(ob + BCOL_WT), RS2, int_b,
        out, RS, nullptr, 0, nullptr, 0, RTOT, N1, DFEAT);
    if (ws_ok)
      k_tail_v8<<<RTOT/16, 256, 0, stream>>>((const short*)d_ws, int_b, out);
    else
      k_tail_v6<<<RTOT/16, 256, 0, stream>>>(int_w, int_b, out);
  }
}

// Round 23
// 639.014 us; speedup vs baseline: 1.0273x; 1.0273x over previous
//
#include <hip/hip_runtime.h>
#include <hip/hip_bf16.h>
#include <cstdint>
#include <cstddef>

#define B_    16
#define L_    512
#define LH    511
#define RTOT  (B_*LH)      // 8176 rows
#define DM    256
#define DFEAT 1024
#define NG    64
#define GPDIM 64
#define NENT  8000
#define NRELS 100
#define RS    8000         // f32 row stride inside d_out
#define RS2   16000        // bf16 row stride inside d_out

// f32 column slots inside each row's 8000-float span of d_out
#define COL_X     0
#define COL_CUR   256
#define COL_Q     512
#define COL_K     768
#define COL_V     1024
#define COL_ATTN  1280
#define COL_FF    1536     // flatF: enc_out(512) | s_emb(256) | r_emb(256)
#define COL_GP    4200     // rows 0..1023, 64 wide
#define COL_GOUT  4300     // rows 0..1023, 64 wide
#define COL_FLAG  5000     // row 0 only
// bf16 regions (bf16-element offsets within a row, stride RS2)
#define BCOL_ENCW 5248     // = 2*2624 : encoder Wt, rows 0..2047 (8 slots x 256), 512 bf16 wide
#define BCOL_MGWT 11104    // = 2*5552 : mgWt rows 0..1023, 1088 bf16
#define BCOL_MGA  12192    // = 2*6096 : merged-A bf16 copy, all rows, 1088 bf16 (dead before F1 writes)
#define BCOL_WT   13824    // = 2*6912 : Wt rows 0..6911, 1024 bf16
#define BCOL_ENH  14848    // = 2*7424 : enh bf16, all rows, 1024 bf16 (fallback path only)
#define N1        6912     // F1 covers out cols [0, 6912); tail covers [6912, 8000)

// ---- d_ws layouts ----
// v1 (ws_ok):  [Bt 1088x1024 bf16][K][V]           (needs 10.6 MB)
#define WS_OFF_K  2228224ull
#define WS_OFF_V  (WS_OFF_K + 4186112ull)
#define WS_NEED2  (WS_OFF_V + 4194304ull)
// v2 (ws_ok3): [Bt 1152x1024 bf16][ENH 8176x1024 bf16, K/V overlap inside]
#define WS2_BT    0ull
#define WS2_ENH   2359296ull
#define WS2_K     WS2_ENH
#define WS2_V     (WS2_K + 4186112ull)
#define WS_NEED3  (WS2_ENH + 16744448ull)   // 19,103,744 bytes

static constexpr float LN1E4_OVER_128 = 0.07195578415606394f; // ln(10000)/128

typedef __attribute__((ext_vector_type(8))) short short8;
typedef __attribute__((ext_vector_type(4))) short sshort4;
typedef __attribute__((ext_vector_type(4))) float f32x4;
typedef __attribute__((ext_vector_type(2))) float f32x2;

__device__ __forceinline__ short bf16b(float x){
  union { __hip_bfloat16 h; short s; } u; u.h = __float2bfloat16(x); return u.s;
}

// fast softplus: hw v_exp_f32 / v_log_f32 (~7 VALU ops vs ~55 for libm)
__device__ __forceinline__ float fast_softplus(float v) {
  return fmaxf(v, 0.f) + __logf(1.0f + __expf(-fabsf(v)));
}

// async global->LDS copy, 16B per lane. LDS dest is wave-uniform base +
// lane*16 (linear); global src is per-lane (we pre-swizzle it).
__device__ __forceinline__ void gload16(const void* g, void* l) {
  __builtin_amdgcn_global_load_lds(
      (const __attribute__((address_space(1))) unsigned int*)g,
      (__attribute__((address_space(3))) unsigned int*)l, 16, 0, 0);
}

// ---------------- mask dtype autodetect (bool(1B) vs int32) ----------------
__global__ __launch_bounds__(256) void k_detect(const unsigned int* __restrict__ m,
                                                float* __restrict__ outbuf) {
  __shared__ int bad;
  if (threadIdx.x == 0) bad = 0;
  __syncthreads();
  int local = 0;
  for (int i = threadIdx.x; i < 2048; i += 256)
    if (m[i] > 1u) local = 1;
  if (local) bad = 1;
  __syncthreads();
  if (threadIdx.x == 0) ((int*)outbuf)[COL_FLAG] = bad;   // 1 => byte-bool layout
}

__device__ __forceinline__ int mask_at(const void* m, int idx, int boolmode) {
  return boolmode ? (int)((const unsigned char*)m)[idx] : ((const int*)m)[idx];
}

// ---------------- x,cur build ----------------
__global__ __launch_bounds__(256) void k_build_x_cur(
    const int* __restrict__ objs, const float* __restrict__ times,
    const float* __restrict__ dts, const float* __restrict__ obj_embed,
    float* __restrict__ out)
{
  int bt = blockIdx.x;
  int b = bt / LH, t = bt - b * LH;
  int d = threadIdx.x;
  int i = d & 127;
  float freq = expf(-(float)i * LN1E4_OVER_128);
  float t0 = times[b*L_ + t];
  float t1 = times[b*L_ + t + 1];
  float dtv = dts[b*L_ + t];
  float a0 = t0*freq, ad = dtv*freq, a1 = t1*freq;
  bool lo = (d < 128);
  float te0 = lo ? sinf(a0) : cosf(a0);
  float ted = lo ? sinf(ad) : cosf(ad);
  float te1 = lo ? sinf(a1) : cosf(a1);
  int obj = objs[b*L_ + t];
  out[(size_t)bt*RS + COL_X   + d] = obj_embed[(size_t)obj*DM + d] + te0 + ted;
  out[(size_t)bt*RS + COL_CUR + d] = te1;
}

// ---------------- bf16 MFMA GEMM, direct-from-global ----------------------
// EPI 2: Cf += acc (residual, no bias); aux[grow*ldaux + auxoff + col] = new Cf
// EPI 3: Cf = acc (plain f32, no bias)
template<bool AF32, int EPI>
__global__ __launch_bounds__(256) void gemm_mfma(
    const void* __restrict__ Aptr, long strideA,
    const short* __restrict__ Bt, long strideB,
    const float* __restrict__ bias,
    float* __restrict__ Cf, long strideC,
    __hip_bfloat16* __restrict__ Cb, long strideCb,
    float* __restrict__ aux, long ldaux, int auxoff,
    int M, int K)
{
  int lane = threadIdx.x & 63;
  int wid  = threadIdx.x >> 6;
  int wm = wid >> 1, wn = wid & 1;
  int r15 = lane & 15, koct = lane >> 4;
  int m0 = blockIdx.y*128 + wm*64;
  int n0 = blockIdx.x*128 + wn*64;
  f32x4 acc[4][4] = {};
  int ar[4];
  #pragma unroll
  for (int mf = 0; mf < 4; ++mf) {
    int r = m0 + mf*16 + r15;
    ar[mf] = r < M ? r : M-1;
  }
  const short* Ab = (const short*)Aptr;
  const float* Af = (const float*)Aptr;
  for (int k0 = 0; k0 < K; k0 += 32) {
    int kk = k0 + koct*8;
    short8 a[4], b[4];
    #pragma unroll
    for (int mf = 0; mf < 4; ++mf) {
      if (AF32) {
        const float* p = Af + (size_t)ar[mf]*strideA + kk;
        f32x4 lo = *(const f32x4*)p;
        f32x4 hi = *(const f32x4*)(p + 4);
        short8 t;
        #pragma unroll
        for (int i = 0; i < 4; ++i) { t[i] = bf16b(lo[i]); t[i+4] = bf16b(hi[i]); }
        a[mf] = t;
      } else {
        a[mf] = *(const short8*)(Ab + (size_t)ar[mf]*strideA + kk);
      }
    }
    #pragma unroll
    for (int nf = 0; nf < 4; ++nf) {
      int n = n0 + nf*16 + r15;
      b[nf] = *(const short8*)(Bt + (size_t)n*strideB + kk);
    }
    #pragma unroll
    for (int mf = 0; mf < 4; ++mf)
      #pragma unroll
      for (int nf = 0; nf < 4; ++nf)
        acc[mf][nf] = __builtin_amdgcn_mfma_f32_16x16x32_bf16(a[mf], b[nf], acc[mf][nf], 0, 0, 0);
  }
  #pragma unroll
  for (int mf = 0; mf < 4; ++mf) {
    #pragma unroll
    for (int r = 0; r < 4; ++r) {
      int grow = m0 + mf*16 + koct*4 + r;
      if (grow >= M) continue;
      #pragma unroll
      for (int nf = 0; nf < 4; ++nf) {
        int gcol = n0 + nf*16 + r15;
        float v = acc[mf][nf][r];
        size_t ci = (size_t)grow*strideC + gcol;
        if (EPI == 2) {
          v += Cf[ci];
          Cf[ci] = v;
          aux[(size_t)grow*ldaux + auxoff + gcol] = v;
        } else {
          Cf[ci] = v;
        }
      }
    }
  }
}

// ---------------- LDS-staged bf16 MFMA GEMM (m97 structure) ---------------
// EPI 0: Cf = softplus(acc+bias), nontemporal (final output, never re-read)
// EPI 1: Cb = bf16(acc+bias); optional Cb2 dual-store
// Store guard: gcol < N (B rows may be padded past N).
template<int EPI>
__global__ __launch_bounds__(256) void gemm_mfma_lds(
    const short* __restrict__ A, long strideA,
    const short* __restrict__ Bt, long strideB,
    const float* __restrict__ bias,
    float* __restrict__ Cf, long strideC,
    __hip_bfloat16* __restrict__ Cb, long strideCb,
    __hip_bfloat16* __restrict__ Cb2, long strideCb2,
    int M, int N, int K)
{
  __shared__ short8 sA[128][8];   // 16KB
  __shared__ short8 sB[128][8];   // 16KB
  int tid = threadIdx.x;
  int lane = tid & 63;
  int w = tid >> 6;
  int wm = w >> 1, wn = w & 1;
  int r15 = lane & 15, koct = lane >> 4;

  int gx = gridDim.x;
  int nwg = gx * gridDim.y;
  int bid = blockIdx.y * gx + blockIdx.x;
  int bx, by;
  if (gridDim.y == 64 && (nwg & 7) == 0) {
    int xcd = bid & 7, c = bid >> 3;
    by = xcd*8 + (c & 7);
    bx = c >> 3;
  } else {
    bx = blockIdx.x; by = blockIdx.y;
  }
  int m0 = by * 128, n0 = bx * 128;

  const short* aSrc[4]; const short* bSrc[4];
  {
    int row = w*32 + (lane >> 3);
    int slot = lane & 7;
    #pragma unroll
    for (int c = 0; c < 4; ++c) {
      int r = row + c*8;
      int ga = m0 + r; if (ga > M-1) ga = M-1;
      int gb = n0 + r;
      int sw = slot ^ (r & 7);
      aSrc[c] = A  + (size_t)ga*strideA + sw*8;
      bSrc[c] = Bt + (size_t)gb*strideB + sw*8;
    }
  }

  f32x4 acc[4][4] = {};
  for (int k0 = 0; k0 < K; k0 += 64) {
    #pragma unroll
    for (int c = 0; c < 4; ++c) {
      gload16(aSrc[c] + k0, (short8*)sA + (w*4 + c)*64);
      gload16(bSrc[c] + k0, (short8*)sB + (w*4 + c)*64);
    }
    __syncthreads();
    #pragma unroll
    for (int ks = 0; ks < 2; ++ks) {
      short8 a[4], b[4];
      #pragma unroll
      for (int mf = 0; mf < 4; ++mf) {
        int lr = wm*64 + mf*16 + r15;
        a[mf] = sA[lr][(ks*4 + koct) ^ (lr & 7)];
      }
      #pragma unroll
      for (int nf = 0; nf < 4; ++nf) {
        int lr = wn*64 + nf*16 + r15;
        b[nf] = sB[lr][(ks*4 + koct) ^ (lr & 7)];
      }
      #pragma unroll
      for (int mf = 0; mf < 4; ++mf)
        #pragma unroll
        for (int nf = 0; nf < 4; ++nf)
          acc[mf][nf] = __builtin_amdgcn_mfma_f32_16x16x32_bf16(a[mf], b[nf], acc[mf][nf], 0, 0, 0);
    }
    __syncthreads();
  }
  #pragma unroll
  for (int mf = 0; mf < 4; ++mf) {
    #pragma unroll
    for (int r = 0; r < 4; ++r) {
      int grow = m0 + wm*64 + mf*16 + koct*4 + r;
      if (grow >= M) continue;
      #pragma unroll
      for (int nf = 0; nf < 4; ++nf) {
        int gcol = n0 + wn*64 + nf*16 + r15;
        if (gcol >= N) continue;
        float v = acc[mf][nf][r] + bias[gcol];
        if (EPI == 0) {
          __builtin_nontemporal_store(fast_softplus(v), &Cf[(size_t)grow*strideC + gcol]);
        } else {
          __hip_bfloat16 hb = __float2bfloat16(v);
          Cb[(size_t)grow*strideCb + gcol] = hb;
          if (Cb2) Cb2[(size_t)grow*strideCb2 + gcol] = hb;
        }
      }
    }
  }
}

// ---------------- W[k][n] f32 -> Wt[n][k] bf16 (strided rows) -------------
__global__ __launch_bounds__(256) void k_transpose_bf16(
    const float* __restrict__ W, int ldw,
    __hip_bfloat16* __restrict__ Wt, long strideT)
{
  __shared__ float s[64][65];
  int n0 = blockIdx.x * 64, k0 = blockIdx.y * 64;
  int tid = threadIdx.x;
  for (int p = 0; p < 16; ++p) {
    int idx = p*256 + tid;
    int kk = idx >> 6, nn = idx & 63;
    s[kk][nn] = W[(size_t)(k0+kk)*ldw + n0 + nn];
  }
  __syncthreads();
  for (int p = 0; p < 16; ++p) {
    int idx = p*256 + tid;
    int nn = idx >> 6, kk = idx & 63;
    Wt[(size_t)(n0+nn)*strideT + k0 + kk] = __float2bfloat16(s[kk][nn]);
  }
}

// ---------------- K/V f32 -> bf16 ws buffers (V transposed) ---------------
__global__ __launch_bounds__(256) void k_kvcast(
    const float* __restrict__ out, short* __restrict__ Kb, short* __restrict__ Vt)
{
  __shared__ float sV[32][65];
  int tt = blockIdx.x, bh = blockIdx.y;
  int b = bh >> 2, h = bh & 3;
  int tid = threadIdx.x;
  #pragma unroll
  for (int i = 0; i < 8; ++i) {
    int idx = i*256 + tid;
    int tp = idx >> 6, d = idx & 63;
    int t = tt*32 + tp;
    float vv = 0.f;
    if (t < LH) {
      const float* row = out + (size_t)(b*LH + t)*RS;
      Kb[((size_t)bh*511 + t)*64 + d] = bf16b(row[COL_K + h*64 + d]);
      vv = row[COL_V + h*64 + d];
    }
    sV[tp][d] = vv;
  }
  __syncthreads();
  #pragma unroll
  for (int i = 0; i < 8; ++i) {
    int idx = i*256 + tid;
    int d = idx >> 5, tp = idx & 31;
    Vt[((size_t)bh*64 + d)*512 + tt*32 + tp] = bf16b(sV[tp][d]);
  }
}

// ---------------- flash-MFMA attention v1 (fallback, f32 K/V) -------------
__global__ __launch_bounds__(64) void k_attn_mfma(float* __restrict__ out)
{
  int qt = blockIdx.x, h = blockIdx.y, b = blockIdx.z;
  int lane = threadIdx.x & 63;
  int r15 = lane & 15, koct = lane >> 4;
  __shared__ short Vt[64][40];
  __shared__ short Pl[16][40];
  const float* base = out + (size_t)b*LH*RS;

  int qrow = qt*16 + r15; if (qrow > LH-1) qrow = LH-1;
  const float* qp = base + (size_t)qrow*RS + COL_Q + h*64 + koct*8;
  short8 qf[2];
  #pragma unroll
  for (int d2 = 0; d2 < 2; ++d2) {
    f32x4 lo = *(const f32x4*)(qp + d2*32);
    f32x4 hi = *(const f32x4*)(qp + d2*32 + 4);
    short8 t;
    #pragma unroll
    for (int i = 0; i < 4; ++i) { t[i] = bf16b(lo[i]); t[i+4] = bf16b(hi[i]); }
    qf[d2] = t;
  }

  f32x4 o[4] = {};
  float m = -3.0e38f, l = 0.f;
  int qg = qt*16 + r15;
  int nt = qt/2 + 1;

  for (int ti = 0; ti < nt; ++ti) {
    int kv0 = ti*32;
    __syncthreads();
    {
      const float* vbase = base + COL_V + h*64 + lane;
      #pragma unroll 4
      for (int j = 0; j < 32; ++j) {
        int kvr = kv0 + j; if (kvr > LH-1) kvr = LH-1;
        Vt[lane][j] = bf16b(vbase[(size_t)kvr*RS]);
      }
    }
    f32x4 s[2] = {};
    #pragma unroll
    for (int kvf = 0; kvf < 2; ++kvf) {
      int kvr = kv0 + kvf*16 + r15; if (kvr > LH-1) kvr = LH-1;
      const float* kp = base + (size_t)kvr*RS + COL_K + h*64 + koct*8;
      #pragma unroll
      for (int d2 = 0; d2 < 2; ++d2) {
        f32x4 lo = *(const f32x4*)(kp + d2*32);
        f32x4 hi = *(const f32x4*)(kp + d2*32 + 4);
        short8 t;
        #pragma unroll
        for (int i = 0; i < 4; ++i) { t[i] = bf16b(lo[i]); t[i+4] = bf16b(hi[i]); }
        s[kvf] = __builtin_amdgcn_mfma_f32_16x16x32_bf16(t, qf[d2], s[kvf], 0, 0, 0);
      }
    }
    float sv[2][4];
    float mx = -3.0e38f;
    #pragma unroll
    for (int kvf = 0; kvf < 2; ++kvf)
      #pragma unroll
      for (int r = 0; r < 4; ++r) {
        int kvg = kv0 + kvf*16 + koct*4 + r;
        float x = s[kvf][r] * 0.125f;
        if (kvg > qg) x = -3.0e38f;
        sv[kvf][r] = x;
        mx = fmaxf(mx, x);
      }
    mx = fmaxf(mx, __shfl_xor(mx, 16));
    mx = fmaxf(mx, __shfl_xor(mx, 32));
    float mn = fmaxf(m, mx);
    float alpha = expf(m - mn);
    m = mn;
    float ls = 0.f;
    sshort4 pk[2];
    #pragma unroll
    for (int kvf = 0; kvf < 2; ++kvf)
      #pragma unroll
      for (int r = 0; r < 4; ++r) {
        float p = expf(sv[kvf][r] - mn);
        ls += p;
        pk[kvf][r] = bf16b(p);
      }
    l = l*alpha + ls;
    *(sshort4*)&Pl[r15][koct*4]      = pk[0];
    *(sshort4*)&Pl[r15][16 + koct*4] = pk[1];
    __syncthreads();
    float arr[4];
    #pragma unroll
    for (int r = 0; r < 4; ++r) arr[r] = __shfl(alpha, koct*4 + r);
    #pragma unroll
    for (int df = 0; df < 4; ++df)
      #pragma unroll
      for (int r = 0; r < 4; ++r) o[df][r] *= arr[r];
    short8 pa = *(const short8*)&Pl[r15][koct*8];
    #pragma unroll
    for (int df = 0; df < 4; ++df) {
      short8 vb = *(const short8*)&Vt[df*16 + r15][koct*8];
      o[df] = __builtin_amdgcn_mfma_f32_16x16x32_bf16(pa, vb, o[df], 0, 0, 0);
    }
  }
  l += __shfl_xor(l, 16);
  l += __shfl_xor(l, 32);
  float linv = 1.f / l;
  float lr[4];
  #pragma unroll
  for (int r = 0; r < 4; ++r) lr[r] = __shfl(linv, koct*4 + r);
  #pragma unroll
  for (int df = 0; df < 4; ++df)
    #pragma unroll
    for (int r = 0; r < 4; ++r) {
      int qq = qt*16 + koct*4 + r;
      if (qq < LH)
        out[((size_t)(b*LH + qq))*RS + COL_ATTN + h*64 + df*16 + r15] = o[df][r] * lr[r];
    }
}

// ---------------- flash-MFMA attention v2 (bf16 K/Vt in ws) ---------------
__global__ __launch_bounds__(64) void k_attn_mfma2(
    const short* __restrict__ Kb, const short* __restrict__ Vt,
    float* __restrict__ out)
{
  int qt = blockIdx.x, h = blockIdx.y, b = blockIdx.z;
  int lane = threadIdx.x & 63;
  int r15 = lane & 15, koct = lane >> 4;
  __shared__ short Pl[16][40];
  int bh = b*4 + h;
  const short* Kbh = Kb + (size_t)bh*511*64;
  const short* Vbh = Vt + (size_t)bh*64*512;
  const float* base = out + (size_t)b*LH*RS;

  int qrow = qt*16 + r15; if (qrow > LH-1) qrow = LH-1;
  const float* qp = base + (size_t)qrow*RS + COL_Q + h*64 + koct*8;
  short8 qf[2];
  #pragma unroll
  for (int d2 = 0; d2 < 2; ++d2) {
    f32x4 lo = *(const f32x4*)(qp + d2*32);
    f32x4 hi = *(const f32x4*)(qp + d2*32 + 4);
    short8 t;
    #pragma unroll
    for (int i = 0; i < 4; ++i) { t[i] = bf16b(lo[i]); t[i+4] = bf16b(hi[i]); }
    qf[d2] = t;
  }

  f32x4 o[4] = {};
  float m = -3.0e38f, l = 0.f;
  int qg = qt*16 + r15;
  int nt = qt/2 + 1;

  for (int ti = 0; ti < nt; ++ti) {
    int kv0 = ti*32;
    f32x4 s[2] = {};
    #pragma unroll
    for (int kvf = 0; kvf < 2; ++kvf) {
      int kvr = kv0 + kvf*16 + r15; if (kvr > LH-1) kvr = LH-1;
      const short* kp = Kbh + (size_t)kvr*64 + koct*8;
      short8 ka0 = *(const short8*)kp;
      short8 ka1 = *(const short8*)(kp + 32);
      s[kvf] = __builtin_amdgcn_mfma_f32_16x16x32_bf16(ka0, qf[0], s[kvf], 0, 0, 0);
      s[kvf] = __builtin_amdgcn_mfma_f32_16x16x32_bf16(ka1, qf[1], s[kvf], 0, 0, 0);
    }
    float sv[2][4];
    float mx = -3.0e38f;
    #pragma unroll
    for (int kvf = 0; kvf < 2; ++kvf)
      #pragma unroll
      for (int r = 0; r < 4; ++r) {
        int kvg = kv0 + kvf*16 + koct*4 + r;
        float x = s[kvf][r] * 0.125f;
        if (kvg > qg) x = -3.0e38f;
        sv[kvf][r] = x;
        mx = fmaxf(mx, x);
      }
    mx = fmaxf(mx, __shfl_xor(mx, 16));
    mx = fmaxf(mx, __shfl_xor(mx, 32));
    float mn = fmaxf(m, mx);
    float alpha = expf(m - mn);
    m = mn;
    float ls = 0.f;
    sshort4 pk[2];
    #pragma unroll
    for (int kvf = 0; kvf < 2; ++kvf)
      #pragma unroll
      for (int r = 0; r < 4; ++r) {
        float p = expf(sv[kvf][r] - mn);
        ls += p;
        pk[kvf][r] = bf16b(p);
      }
    l = l*alpha + ls;
    *(sshort4*)&Pl[r15][koct*4]      = pk[0];
    *(sshort4*)&Pl[r15][16 + koct*4] = pk[1];
    __syncthreads();   // 1-wave barrier: orders P write->read (cheap)
    float arr[4];
    #pragma unroll
    for (int r = 0; r < 4; ++r) arr[r] = __shfl(alpha, koct*4 + r);
    #pragma unroll
    for (int df = 0; df < 4; ++df)
      #pragma unroll
      for (int r = 0; r < 4; ++r) o[df][r] *= arr[r];
    short8 pa = *(const short8*)&Pl[r15][koct*8];
    #pragma unroll
    for (int df = 0; df < 4; ++df) {
      short8 vb = *(const short8*)(Vbh + (size_t)(df*16 + r15)*512 + kv0 + koct*8);
      o[df] = __builtin_amdgcn_mfma_f32_16x16x32_bf16(pa, vb, o[df], 0, 0, 0);
    }
  }
  l += __shfl_xor(l, 16);
  l += __shfl_xor(l, 32);
  float linv = 1.f / l;
  float lr[4];
  #pragma unroll
  for (int r = 0; r < 4; ++r) lr[r] = __shfl(linv, koct*4 + r);
  #pragma unroll
  for (int df = 0; df < 4; ++df)
    #pragma unroll
    for (int r = 0; r < 4; ++r) {
      int qq = qt*16 + koct*4 + r;
      if (qq < LH)
        out[((size_t)(b*LH + qq))*RS + COL_ATTN + h*64 + df*16 + r15] = o[df][r] * lr[r];
    }
}

// ---------------- flatF[:,512:768]=sub_embed, [:,768:1024]=rel_embed ------
__global__ __launch_bounds__(256) void k_feats(
    const int* __restrict__ subs, const int* __restrict__ marks,
    const float* __restrict__ sub_embed, const float* __restrict__ rel_embed,
    float* __restrict__ out)
{
  int bt = blockIdx.x;
  int b = bt / LH;
  int d = threadIdx.x;
  out[(size_t)bt*RS + COL_FF + 512 + d] = sub_embed[(size_t)subs[b*L_]*256 + d];
  out[(size_t)bt*RS + COL_FF + 768 + d] = rel_embed[(size_t)marks[b*L_]*256 + d];
}

// ---------------- fused segment-mean + gp projection (no atomics) ---------
// One block per (b,group): fixed-order masked column sum of matching flatF
// rows, then gp[key] = (sum/cnt) @ gp_w + gp_b. Deterministic.
__global__ __launch_bounds__(256) void k_seg2(
    const int* __restrict__ subs, const int* __restrict__ marks,
    const void* __restrict__ mask, const int* __restrict__ group_map,
    const float* __restrict__ gp_w, const float* __restrict__ gp_b,
    float* __restrict__ out)
{
  __shared__ unsigned char match[512];
  __shared__ float macc[1024];
  __shared__ float pacc[4][64];
  __shared__ int cnt;
  int key = blockIdx.x;            // b*64 + g
  int b = key >> 6, g = key & 63;
  int tid = threadIdx.x;
  int boolmode = ((const int*)out)[COL_FLAG];
  if (tid == 0) cnt = 0;
  __syncthreads();
  int lc = 0;
  for (int t = tid; t < LH; t += 256) {
    int mt = 0;
    if (mask_at(mask, b*L_ + t, boolmode)) {
      int gid = group_map[subs[b*L_ + t]*NRELS + marks[b*L_ + t]];
      mt = (gid == g) ? 1 : 0;
    }
    match[t] = (unsigned char)mt;
    lc += mt;
  }
  if (lc) atomicAdd(&cnt, lc);     // LDS int add: exact, order-free
  __syncthreads();

  // column-owned accumulation, fixed row order (deterministic)
  f32x4 acc = {0.f, 0.f, 0.f, 0.f};
  int c0 = tid * 4;
  for (int t = 0; t < LH; ++t) {
    if (match[t]) {
      f32x4 v = *(const f32x4*)(out + (size_t)(b*LH + t)*RS + COL_FF + c0);
      acc.x += v.x; acc.y += v.y; acc.z += v.z; acc.w += v.w;
    }
  }
  *(f32x4*)&macc[c0] = acc;
  __syncthreads();

  // gp projection: j = tid&63, k-chunk = tid>>6
  int j = tid & 63, ch = tid >> 6;
  float p = 0.f;
  int kb = ch * 256;
  for (int k2 = kb; k2 < kb + 256; ++k2)
    p += macc[k2] * gp_w[k2*GPDIM + j];
  pacc[ch][j] = p;
  __syncthreads();
  if (tid < 64) {
    float inv = 1.0f / fmaxf((float)cnt, 1.0f);
    float s = pacc[0][tid] + pacc[1][tid] + pacc[2][tid] + pacc[3][tid];
    out[(size_t)key*RS + COL_GP + tid] = s * inv + gp_b[tid];
  }
}

// ---------------- whole group transformer per batch, all in LDS -----------
__global__ __launch_bounds__(256) void k_group(
    const float* __restrict__ ga_in_w, const float* __restrict__ ga_in_b,
    const float* __restrict__ ga_out_w, const float* __restrict__ ga_out_b,
    const float* __restrict__ ffn_w1, const float* __restrict__ ffn_b1,
    const float* __restrict__ ffn_w2, const float* __restrict__ ffn_b2,
    const float* __restrict__ n1_w, const float* __restrict__ n1_b,
    const float* __restrict__ n2_w, const float* __restrict__ n2_b,
    float* __restrict__ out)
{
  __shared__ float sGP[64][64];
  __shared__ float sQ[64][64];
  __shared__ float sK[64][64];
  __shared__ float sV[64][64];
  int b = blockIdx.x, tid = threadIdx.x;
  for (int i = tid; i < 4096; i += 256)
    sGP[i>>6][i&63] = out[(size_t)(b*64 + (i>>6))*RS + COL_GP + (i&63)];
  __syncthreads();
  for (int i = tid; i < 64*192; i += 256) {
    int g = i / 192, c = i - g*192;
    float acc = ga_in_b[c];
    for (int k2 = 0; k2 < 64; ++k2) acc += sGP[g][k2] * ga_in_w[k2*192 + c];
    if (c < 64)       sQ[g][c]      = acc;
    else if (c < 128) sK[g][c-64]   = acc;
    else              sV[g][c-128]  = acc;
  }
  __syncthreads();
  if (tid < 128) {
    int qi = tid >> 1, h = tid & 1, base = h*32;
    float sc[64];
    float mx = -3.0e38f;
    #pragma unroll
    for (int k2 = 0; k2 < 64; ++k2) {
      float d2 = 0.f;
      #pragma unroll
      for (int d = 0; d < 32; ++d) d2 += sQ[qi][base+d] * sK[k2][base+d];
      d2 *= 0.17677669529663689f;
      sc[k2] = d2;
      mx = fmaxf(mx, d2);
    }
    float den = 0.f;
    #pragma unroll
    for (int k2 = 0; k2 < 64; ++k2) { sc[k2] = expf(sc[k2]-mx); den += sc[k2]; }
    float inv = 1.f/den;
    #pragma unroll
    for (int d = 0; d < 32; ++d) {
      float acc = 0.f;
      #pragma unroll
      for (int k2 = 0; k2 < 64; ++k2) acc += sc[k2] * sV[k2][base+d];
      sQ[qi][base+d] = acc * inv;
    }
  }
  __syncthreads();
  for (int i = tid; i < 4096; i += 256) {
    int g = i>>6, c = i&63;
    float acc = ga_out_b[c];
    for (int k2 = 0; k2 < 64; ++k2) acc += sQ[g][k2] * ga_out_w[k2*64 + c];
    sK[g][c] = sGP[g][c] + acc;
  }
  __syncthreads();
  if (tid < 64) {
    int g = tid;
    float mu = 0.f; for (int c=0;c<64;c++) mu += sK[g][c]; mu *= (1.f/64.f);
    float var = 0.f; for (int c=0;c<64;c++){float d2=sK[g][c]-mu; var += d2*d2;} var *= (1.f/64.f);
    float inv = 1.0f / sqrtf(var + 1e-5f);
    for (int c=0;c<64;c++) sK[g][c] = (sK[g][c]-mu)*inv*n1_w[c] + n1_b[c];
  }
  __syncthreads();
  for (int i = tid; i < 4096; i += 256) {
    int g = i>>6, c = i&63;
    float acc = ffn_b1[c];
    for (int k2 = 0; k2 < 64; ++k2) acc += sK[g][k2] * ffn_w1[k2*64 + c];
    sV[g][c] = fmaxf(acc, 0.f);
  }
  __syncthreads();
  for (int i = tid; i < 4096; i += 256) {
    int g = i>>6, c = i&63;
    float acc = ffn_b2[c];
    for (int k2 = 0; k2 < 64; ++k2) acc += sV[g][k2] * ffn_w2[k2*64 + c];
    sGP[g][c] = sK[g][c] + acc;
  }
  __syncthreads();
  if (tid < 64) {
    int g = tid;
    float mu = 0.f; for (int c=0;c<64;c++) mu += sGP[g][c]; mu *= (1.f/64.f);
    float var = 0.f; for (int c=0;c<64;c++){float d2=sGP[g][c]-mu; var += d2*d2;} var *= (1.f/64.f);
    float inv = 1.0f / sqrtf(var + 1e-5f);
    for (int c=0;c<64;c++)
      out[(size_t)(b*64 + g)*RS + COL_GOUT + c] = (sGP[g][c]-mu)*inv*n2_w[c] + n2_b[c];
  }
}

// ---------------- fused gather + merged-A bf16 cast ------------------------
// gathered stays in LDS; MGA row = bf16([flatF(1024) | gathered(64)]).
__global__ __launch_bounds__(256) void k_gather_cast(
    const int* __restrict__ subs, const int* __restrict__ marks,
    const void* __restrict__ mask, const int* __restrict__ group_map,
    float* __restrict__ out)
{
  __shared__ float gv[64];
  int bt = blockIdx.x;
  int b = bt / LH, t = bt - b*LH;
  int tid = threadIdx.x;
  int boolmode = ((const int*)out)[COL_FLAG];
  if (tid < 64) {
    float val = 0.f;
    if (mask_at(mask, b*L_ + t, boolmode)) {
      int gid = group_map[subs[b*L_+t]*NRELS + marks[b*L_+t]];
      val = out[(size_t)(b*NG + gid)*RS + COL_GOUT + tid];
    }
    gv[tid] = val;
  }
  __syncthreads();
  const float* src = out + (size_t)bt*RS + COL_FF;
  short* dst = (short*)out + (size_t)bt*RS2 + BCOL_MGA;
  for (int i = tid; i < 1088; i += 256)
    dst[i] = bf16b(i < 1024 ? src[i] : gv[i - 1024]);
}

// ---------------- tail v6 (fallback when ws too small) --------------------
__global__ __launch_bounds__(256) void k_tail_v6(
    const float* __restrict__ int_w, const float* __restrict__ int_b,
    float* __restrict__ out)
{
  __shared__ short8 sA[16][128];
  __shared__ short8 sB[2][128][8];
  int m0 = blockIdx.x * 16;
  int tid = threadIdx.x;
  int lane = tid & 63;
  int w = tid >> 6;
  int r15 = lane & 15, koct = lane >> 4;
  const short* eb = (const short*)out + BCOL_ENH;

  for (int idx = tid; idx < 16*128; idx += 256) {
    int r = idx >> 7, c8 = idx & 127;
    int row = m0 + r; if (row > RTOT-1) row = RTOT-1;
    sA[r][c8 ^ (r & 7)] = *(const short8*)(eb + (size_t)row*RS2 + c8*8);
  }

  int tn2 = tid & 63;
  int tk4 = tid >> 6;
  int xA = r15 & 7;

  f32x2 v[16];
  auto issueB = [&](int s) {
    int ntile = s >> 4, ks = s & 15;
    int nb = N1 + ntile*128 + tn2*2;
    int ncl = nb <= NENT-2 ? nb : NENT-2;
    const float* bp = int_w + (size_t)(ks*64 + tk4*16)*NENT + ncl;
    #pragma unroll
    for (int i = 0; i < 16; ++i) v[i] = *(const f32x2*)(bp + (size_t)i*NENT);
  };

  issueB(0);
  __syncthreads();

  f32x4 acc[2] = {};
  for (int s = 0; s < 144; ++s) {
    int ks = s & 15;
    int buf = s & 1;
    {
      short h0[16], h1[16];
      #pragma unroll
      for (int i = 0; i < 16; ++i) { h0[i] = bf16b(v[i][0]); h1[i] = bf16b(v[i][1]); }
      short8 p0lo, p0hi, p1lo, p1hi;
      #pragma unroll
      for (int i = 0; i < 8; ++i) {
        p0lo[i] = h0[i]; p0hi[i] = h0[i+8];
        p1lo[i] = h1[i]; p1hi[i] = h1[i+8];
      }
      int nl0 = tn2*2, nl1 = tn2*2 + 1;
      sB[buf][nl0][(tk4*2 + 0) ^ (nl0 & 7)] = p0lo;
      sB[buf][nl0][(tk4*2 + 1) ^ (nl0 & 7)] = p0hi;
      sB[buf][nl1][(tk4*2 + 0) ^ (nl1 & 7)] = p1lo;
      sB[buf][nl1][(tk4*2 + 1) ^ (nl1 & 7)] = p1hi;
    }
    if (s + 1 < 144) issueB(s + 1);
    __syncthreads();
    #pragma unroll
    for (int ksub = 0; ksub < 2; ++ksub) {
      int c8A = ks*8 + ksub*4 + koct;
      short8 a0 = sA[r15][c8A ^ xA];
      #pragma unroll
      for (int nf = 0; nf < 2; ++nf) {
        int nloc = w*32 + nf*16 + r15;
        short8 b = sB[buf][nloc][(ksub*4 + koct) ^ (nloc & 7)];
        acc[nf] = __builtin_amdgcn_mfma_f32_16x16x32_bf16(a0, b, acc[nf], 0, 0, 0);
      }
    }
    if (ks == 15) {
      int n0 = N1 + (s >> 4)*128;
      #pragma unroll
      for (int nf = 0; nf < 2; ++nf) {
        int n = n0 + w*32 + nf*16 + r15;
        if (n < NENT) {
          float bv = int_b[n];
          #pragma unroll
          for (int r = 0; r < 4; ++r) {
            int g = m0 + koct*4 + r;
            if (g < RTOT)
              __builtin_nontemporal_store(fast_softplus(acc[nf][r] + bv),
                                          &out[(size_t)g*RS + n]);
          }
        }
        acc[nf] = (f32x4){0.f, 0.f, 0.f, 0.f};
      }
    }
  }
}

// ---------------- tail v8: B pre-transposed bf16 in d_ws ------------------
__global__ __launch_bounds__(256) void k_tail_v8(
    const short* __restrict__ Bt, const float* __restrict__ int_b,
    float* __restrict__ out)
{
  __shared__ short8 sA[16][128];
  __shared__ short8 sB[2][128][8];
  int m0 = blockIdx.x * 16;
  int tid = threadIdx.x;
  int lane = tid & 63;
  int w = tid >> 6;
  int r15 = lane & 15, koct = lane >> 4;
  const short* eb = (const short*)out + BCOL_ENH;

  for (int idx = tid; idx < 16*128; idx += 256) {
    int r = idx >> 7, c8 = idx & 127;
    int row = m0 + r; if (row > RTOT-1) row = RTOT-1;
    sA[r][c8 ^ (r & 7)] = *(const short8*)(eb + (size_t)row*RS2 + c8*8);
  }

  int rl8 = w*8 + (lane >> 3);
  int slot = lane & 7;
  int xA = r15 & 7;

  auto issueB = [&](int s) {
    int ntile = s >> 4, ks = s & 15;
    #pragma unroll
    for (int c = 0; c < 4; ++c) {
      int rowL = c*32 + rl8;
      int wsrow = ntile*128 + rowL;
      if (wsrow > 1087) wsrow = 1087;
      int sw = slot ^ (rowL & 7);
      gload16(Bt + (size_t)wsrow*1024 + ks*64 + sw*8,
              (short8*)&sB[s & 1][c*32 + w*8][0]);
    }
  };

  issueB(0);
  __syncthreads();

  f32x4 acc[2] = {};
  for (int s = 0; s < 144; ++s) {
    int ks = s & 15, buf = s & 1;
    if (s + 1 < 144) issueB(s + 1);
    #pragma unroll
    for (int ksub = 0; ksub < 2; ++ksub) {
      int c8A = ks*8 + ksub*4 + koct;
      short8 a0 = sA[r15][c8A ^ xA];
      #pragma unroll
      for (int nf = 0; nf < 2; ++nf) {
        int nloc = w*32 + nf*16 + r15;
        short8 b = sB[buf][nloc][(ksub*4 + koct) ^ (nloc & 7)];
        acc[nf] = __builtin_amdgcn_mfma_f32_16x16x32_bf16(a0, b, acc[nf], 0, 0, 0);
      }
    }
    if (ks == 15) {
      int n0 = N1 + (s >> 4)*128;
      #pragma unroll
      for (int nf = 0; nf < 2; ++nf) {
        int n = n0 + w*32 + nf*16 + r15;
        if (n < NENT) {
          float bv = int_b[n];
          #pragma unroll
          for (int r = 0; r < 4; ++r) {
            int g = m0 + koct*4 + r;
            if (g < RTOT)
              __builtin_nontemporal_store(fast_softplus(acc[nf][r] + bv),
                                          &out[(size_t)g*RS + n]);
          }
        }
        acc[nf] = (f32x4){0.f, 0.f, 0.f, 0.f};
      }
    }
    __syncthreads();
  }
}

extern "C" void kernel_launch(void* const* d_in, const int* in_sizes, int n_in,
                              void* d_out, int out_size, void* d_ws, size_t ws_size,
                              hipStream_t stream)
{
  const int*   subs      = (const int*)  d_in[0];
  const int*   marks     = (const int*)  d_in[1];
  const int*   objs      = (const int*)  d_in[2];
  const float* times     = (const float*)d_in[3];
  const float* dts       = (const float*)d_in[4];
  const void*  mask      =               d_in[5];
  const int*   group_map = (const int*)  d_in[6];
  const float* obj_embed = (const float*)d_in[7];
  const float* Wq        = (const float*)d_in[8];
  const float* Wk        = (const float*)d_in[9];
  const float* Wv        = (const float*)d_in[10];
  const float* Wo        = (const float*)d_in[11];
  const float* sub_embed = (const float*)d_in[12];
  const float* rel_embed = (const float*)d_in[13];
  const float* gp_w      = (const float*)d_in[14];
  const float* gp_b      = (const float*)d_in[15];
  const float* ga_in_w   = (const float*)d_in[16];
  const float* ga_in_b   = (const float*)d_in[17];
  const float* ga_out_w  = (const float*)d_in[18];
  const float* ga_out_b  = (const float*)d_in[19];
  const float* ffn_w1    = (const float*)d_in[20];
  const float* ffn_b1    = (const float*)d_in[21];
  const float* ffn_w2    = (const float*)d_in[22];
  const float* ffn_b2    = (const float*)d_in[23];
  const float* n1_w      = (const float*)d_in[24];
  const float* n1_b      = (const float*)d_in[25];
  const float* n2_w      = (const float*)d_in[26];
  const float* n2_b      = (const float*)d_in[27];
  const float* mg_w      = (const float*)d_in[28];
  const float* mg_b      = (const float*)d_in[29];
  const float* int_w     = (const float*)d_in[30];
  const float* int_b     = (const float*)d_in[31];
  float* out = (float*)d_out;
  __hip_bfloat16* ob = (__hip_bfloat16*)d_out;

  bool ws_ok  = ws_size >= (size_t)1088 * 1024 * sizeof(__hip_bfloat16);
  bool ws_ok2 = ws_size >= WS_NEED2;
  bool ws_ok3 = ws_size >= WS_NEED3;

  short* wsK = ws_ok3 ? (short*)((char*)d_ws + WS2_K) : (short*)((char*)d_ws + WS_OFF_K);
  short* wsV = ws_ok3 ? (short*)((char*)d_ws + WS2_V) : (short*)((char*)d_ws + WS_OFF_V);
  __hip_bfloat16* wsENH = (__hip_bfloat16*)((char*)d_ws + WS2_ENH);

  k_detect<<<1, 256, 0, stream>>>((const unsigned int*)mask, out);
  k_transpose_bf16<<<dim3(N1/64, DFEAT/64), 256, 0, stream>>>(int_w, NENT, ob + BCOL_WT, RS2);
  k_transpose_bf16<<<dim3(DFEAT/64, 1088/64), 256, 0, stream>>>(mg_w, DFEAT, ob + BCOL_MGWT, RS2);
  if (ws_ok) {
    k_transpose_bf16<<<dim3(1088/64, DFEAT/64), 256, 0, stream>>>(
        int_w + N1, NENT, (__hip_bfloat16*)d_ws, 1024);
  }
  for (int l = 0; l < 2; ++l) {
    const float* ws[4] = { Wq + (size_t)l*DM*DM, Wk + (size_t)l*DM*DM,
                           Wv + (size_t)l*DM*DM, Wo + (size_t)l*DM*DM };
    for (int j = 0; j < 4; ++j)
      k_transpose_bf16<<<dim3(4, 4), 256, 0, stream>>>(
          ws[j], DM, ob + BCOL_ENCW + (size_t)((l*4 + j)*256)*RS2, RS2);
  }

  k_build_x_cur<<<RTOT, 256, 0, stream>>>(objs, times, dts, obj_embed, out);

  for (int l = 0; l < 2; ++l) {
    const short* encw = (const short*)(ob + BCOL_ENCW);
    const short* wtq = encw + (size_t)((l*4 + 0)*256)*RS2;
    const short* wtk = encw + (size_t)((l*4 + 1)*256)*RS2;
    const short* wto = encw + (size_t)((l*4 + 3)*256)*RS2;
    gemm_mfma<true, 3><<<dim3(2, 64), 256, 0, stream>>>(
        out + COL_CUR, RS, wtq, RS2, nullptr,
        out + COL_Q, RS, nullptr, 0, nullptr, 0, 0, RTOT, DM);
    gemm_mfma<true, 3><<<dim3(4, 64), 256, 0, stream>>>(
        out + COL_X, RS, wtk, RS2, nullptr,
        out + COL_K, RS, nullptr, 0, nullptr, 0, 0, RTOT, DM);
    if (ws_ok2) {
      k_kvcast<<<dim3(16, 64), 256, 0, stream>>>(out, wsK, wsV);
      k_attn_mfma2<<<dim3(32, 4, B_), 64, 0, stream>>>(wsK, wsV, out);
    } else {
      k_attn_mfma<<<dim3(32, 4, B_), 64, 0, stream>>>(out);
    }
    gemm_mfma<true, 2><<<dim3(2, 64), 256, 0, stream>>>(
        out + COL_ATTN, RS, wto, RS2, nullptr,
        out + COL_CUR, RS, nullptr, 0, out + COL_FF, RS, l*DM, RTOT, DM);
  }

  k_feats<<<RTOT, 256, 0, stream>>>(subs, marks, sub_embed, rel_embed, out);
  // fused segment-mean + gp projection (replaces zero+segsum+gp)
  k_seg2<<<1024, 256, 0, stream>>>(subs, marks, mask, group_map, gp_w, gp_b, out);
  k_group<<<B_, 256, 0, stream>>>(ga_in_w, ga_in_b, ga_out_w, ga_out_b,
                                  ffn_w1, ffn_b1, ffn_w2, ffn_b2,
                                  n1_w, n1_b, n2_w, n2_b, out);
  // fused gather + merged-A bf16 cast (replaces gather+castA)
  k_gather_cast<<<RTOT, 256, 0, stream>>>(subs, marks, mask, group_map, out);

  if (ws_ok3) {
    gemm_mfma_lds<1><<<dim3(DFEAT/128, 64), 256, 0, stream>>>(
        (const short*)(ob + BCOL_MGA), RS2, (const short*)(ob + BCOL_MGWT), RS2, mg_b,
        nullptr, 0, wsENH, 1024, nullptr, 0, RTOT, DFEAT, 1088);
    gemm_mfma_lds<0><<<dim3(N1/128, (RTOT+127)/128), 256, 0, stream>>>(
        (const short*)wsENH, 1024, (const short*)(ob + BCOL_WT), RS2, int_b,
        out, RS, nullptr, 0, nullptr, 0, RTOT, N1, DFEAT);
    gemm_mfma_lds<0><<<dim3(9, 64), 256, 0, stream>>>(
        (const short*)wsENH, 1024, (const short*)d_ws, 1024, int_b + N1,
        out + N1, RS, nullptr, 0, nullptr, 0, RTOT, 1088, DFEAT);
  } else {
    gemm_mfma_lds<1><<<dim3(DFEAT/128, 64), 256, 0, stream>>>(
        (const short*)(ob + BCOL_MGA), RS2, (const short*)(ob + BCOL_MGWT), RS2, mg_b,
        nullptr, 0, ob + BCOL_ENH, RS2, nullptr, 0, RTOT, DFEAT, 1088);
    gemm_mfma_lds<0><<<dim3(N1/128, (RTOT+127)/128), 256, 0, stream>>>(
        (const short*)(ob + BCOL_ENH), RS2, (const short*)(ob + BCOL_WT), RS2, int_b,
        out, RS, nullptr, 0, nullptr, 0, RTOT, N1, DFEAT);
    if (ws_ok)
      k_tail_v8<<<RTOT/16, 256, 0, stream>>>((const short*)d_ws, int_b, out);
    else
      k_tail_v6<<<RTOT/16, 256, 0, stream>>>(int_w, int_b, out);
  }
}

// Round 24
// 638.766 us; speedup vs baseline: 1.0277x; 1.0004x over previous
//
#include <hip/hip_runtime.h>
#include <hip/hip_bf16.h>
#include <cstdint>
#include <cstddef>

#define B_    16
#define L_    512
#define LH    511
#define RTOT  (B_*LH)      // 8176 rows
#define DM    256
#define DFEAT 1024
#define NG    64
#define GPDIM 64
#define NENT  8000
#define NRELS 100
#define RS    8000         // f32 row stride inside d_out
#define RS2   16000        // bf16 row stride inside d_out

// f32 column slots inside each row's 8000-float span of d_out
#define COL_X     0
#define COL_CUR   256
#define COL_Q     512
#define COL_K     768
#define COL_V     1024
#define COL_ATTN  1280
#define COL_FF    1536     // flatF: enc_out(512) | s_emb(256) | r_emb(256)
#define COL_GP    4200     // rows 0..1023, 64 wide
#define COL_GOUT  4300     // rows 0..1023, 64 wide
#define COL_FLAG  5000     // row 0 only
// bf16 regions (bf16-element offsets within a row, stride RS2)
#define BCOL_ENCW 5248     // encoder Wt, rows 0..2047 (8 slots x 256), 512 bf16 wide
#define BCOL_MGWT 11104    // mgWt rows 0..1023, 1088 bf16
#define BCOL_MGA  12192    // merged-A bf16 copy, all rows, 1088 bf16
#define BCOL_WT   13824    // Wt rows 0..6911, 1024 bf16
#define BCOL_ENH  14848    // enh bf16 (fallback path only)
#define N1        6912     // F1 covers out cols [0, 6912); tail covers [6912, 8000)

// ---- d_ws layouts ----
// v1 (ws_ok):  [Bt 1088x1024 bf16][K][V]           (needs 10.6 MB)
#define WS_OFF_K  2228224ull
#define WS_OFF_V  (WS_OFF_K + 4186112ull)
#define WS_NEED2  (WS_OFF_V + 4194304ull)
// v2 (ws_ok3): padded stride WSP=1088 bf16 (2176B, non-pow2: avoids HBM
// channel / L2-set aliasing that cost F1 ~40us with stride 2048B).
#define WSP       1088
#define WS2_BT    0ull
#define WS2_ENH   2506752ull                       // 1152*WSP*2
#define WS2_K     WS2_ENH
#define WS2_V     (WS2_K + 4186112ull)
#define WS_NEED3  (WS2_ENH + 17790976ull)          // + 8176*WSP*2 = 20,297,728

static constexpr float LN1E4_OVER_128 = 0.07195578415606394f; // ln(10000)/128

typedef __attribute__((ext_vector_type(8))) short short8;
typedef __attribute__((ext_vector_type(4))) short sshort4;
typedef __attribute__((ext_vector_type(4))) float f32x4;
typedef __attribute__((ext_vector_type(2))) float f32x2;

__device__ __forceinline__ short bf16b(float x){
  union { __hip_bfloat16 h; short s; } u; u.h = __float2bfloat16(x); return u.s;
}

// fast softplus: hw v_exp_f32 / v_log_f32 (~7 VALU ops vs ~55 for libm)
__device__ __forceinline__ float fast_softplus(float v) {
  return fmaxf(v, 0.f) + __logf(1.0f + __expf(-fabsf(v)));
}

// async global->LDS copy, 16B per lane. LDS dest is wave-uniform base +
// lane*16 (linear); global src is per-lane (we pre-swizzle it).
__device__ __forceinline__ void gload16(const void* g, void* l) {
  __builtin_amdgcn_global_load_lds(
      (const __attribute__((address_space(1))) unsigned int*)g,
      (__attribute__((address_space(3))) unsigned int*)l, 16, 0, 0);
}

// ---------------- mask dtype autodetect (bool(1B) vs int32) ----------------
__global__ __launch_bounds__(256) void k_detect(const unsigned int* __restrict__ m,
                                                float* __restrict__ outbuf) {
  __shared__ int bad;
  if (threadIdx.x == 0) bad = 0;
  __syncthreads();
  int local = 0;
  for (int i = threadIdx.x; i < 2048; i += 256)
    if (m[i] > 1u) local = 1;
  if (local) bad = 1;
  __syncthreads();
  if (threadIdx.x == 0) ((int*)outbuf)[COL_FLAG] = bad;   // 1 => byte-bool layout
}

__device__ __forceinline__ int mask_at(const void* m, int idx, int boolmode) {
  return boolmode ? (int)((const unsigned char*)m)[idx] : ((const int*)m)[idx];
}

// ---------------- x,cur build ----------------
__global__ __launch_bounds__(256) void k_build_x_cur(
    const int* __restrict__ objs, const float* __restrict__ times,
    const float* __restrict__ dts, const float* __restrict__ obj_embed,
    float* __restrict__ out)
{
  int bt = blockIdx.x;
  int b = bt / LH, t = bt - b * LH;
  int d = threadIdx.x;
  int i = d & 127;
  float freq = expf(-(float)i * LN1E4_OVER_128);
  float t0 = times[b*L_ + t];
  float t1 = times[b*L_ + t + 1];
  float dtv = dts[b*L_ + t];
  float a0 = t0*freq, ad = dtv*freq, a1 = t1*freq;
  bool lo = (d < 128);
  float te0 = lo ? sinf(a0) : cosf(a0);
  float ted = lo ? sinf(ad) : cosf(ad);
  float te1 = lo ? sinf(a1) : cosf(a1);
  int obj = objs[b*L_ + t];
  out[(size_t)bt*RS + COL_X   + d] = obj_embed[(size_t)obj*DM + d] + te0 + ted;
  out[(size_t)bt*RS + COL_CUR + d] = te1;
}

// ---------------- bf16 MFMA GEMM, direct-from-global ----------------------
// EPI 2: Cf += acc (residual, no bias); aux[grow*ldaux + auxoff + col] = new Cf
// EPI 3: Cf = acc (plain f32, no bias)
template<bool AF32, int EPI>
__global__ __launch_bounds__(256) void gemm_mfma(
    const void* __restrict__ Aptr, long strideA,
    const short* __restrict__ Bt, long strideB,
    const float* __restrict__ bias,
    float* __restrict__ Cf, long strideC,
    __hip_bfloat16* __restrict__ Cb, long strideCb,
    float* __restrict__ aux, long ldaux, int auxoff,
    int M, int K)
{
  int lane = threadIdx.x & 63;
  int wid  = threadIdx.x >> 6;
  int wm = wid >> 1, wn = wid & 1;
  int r15 = lane & 15, koct = lane >> 4;
  int m0 = blockIdx.y*128 + wm*64;
  int n0 = blockIdx.x*128 + wn*64;
  f32x4 acc[4][4] = {};
  int ar[4];
  #pragma unroll
  for (int mf = 0; mf < 4; ++mf) {
    int r = m0 + mf*16 + r15;
    ar[mf] = r < M ? r : M-1;
  }
  const short* Ab = (const short*)Aptr;
  const float* Af = (const float*)Aptr;
  for (int k0 = 0; k0 < K; k0 += 32) {
    int kk = k0 + koct*8;
    short8 a[4], b[4];
    #pragma unroll
    for (int mf = 0; mf < 4; ++mf) {
      if (AF32) {
        const float* p = Af + (size_t)ar[mf]*strideA + kk;
        f32x4 lo = *(const f32x4*)p;
        f32x4 hi = *(const f32x4*)(p + 4);
        short8 t;
        #pragma unroll
        for (int i = 0; i < 4; ++i) { t[i] = bf16b(lo[i]); t[i+4] = bf16b(hi[i]); }
        a[mf] = t;
      } else {
        a[mf] = *(const short8*)(Ab + (size_t)ar[mf]*strideA + kk);
      }
    }
    #pragma unroll
    for (int nf = 0; nf < 4; ++nf) {
      int n = n0 + nf*16 + r15;
      b[nf] = *(const short8*)(Bt + (size_t)n*strideB + kk);
    }
    #pragma unroll
    for (int mf = 0; mf < 4; ++mf)
      #pragma unroll
      for (int nf = 0; nf < 4; ++nf)
        acc[mf][nf] = __builtin_amdgcn_mfma_f32_16x16x32_bf16(a[mf], b[nf], acc[mf][nf], 0, 0, 0);
  }
  #pragma unroll
  for (int mf = 0; mf < 4; ++mf) {
    #pragma unroll
    for (int r = 0; r < 4; ++r) {
      int grow = m0 + mf*16 + koct*4 + r;
      if (grow >= M) continue;
      #pragma unroll
      for (int nf = 0; nf < 4; ++nf) {
        int gcol = n0 + nf*16 + r15;
        float v = acc[mf][nf][r];
        size_t ci = (size_t)grow*strideC + gcol;
        if (EPI == 2) {
          v += Cf[ci];
          Cf[ci] = v;
          aux[(size_t)grow*ldaux + auxoff + gcol] = v;
        } else {
          Cf[ci] = v;
        }
      }
    }
  }
}

// ---------------- LDS-staged bf16 MFMA GEMM (m97 structure) ---------------
// EPI 0: Cf = softplus(acc+bias), nontemporal (final output, never re-read)
// EPI 1: Cb = bf16(acc+bias)
// Store guard: gcol < N (B rows may be padded past N).
template<int EPI>
__global__ __launch_bounds__(256) void gemm_mfma_lds(
    const short* __restrict__ A, long strideA,
    const short* __restrict__ Bt, long strideB,
    const float* __restrict__ bias,
    float* __restrict__ Cf, long strideC,
    __hip_bfloat16* __restrict__ Cb, long strideCb,
    int M, int N, int K)
{
  __shared__ short8 sA[128][8];   // 16KB
  __shared__ short8 sB[128][8];   // 16KB
  int tid = threadIdx.x;
  int lane = tid & 63;
  int w = tid >> 6;
  int wm = w >> 1, wn = w & 1;
  int r15 = lane & 15, koct = lane >> 4;

  int gx = gridDim.x;
  int nwg = gx * gridDim.y;
  int bid = blockIdx.y * gx + blockIdx.x;
  int bx, by;
  if (gridDim.y == 64 && (nwg & 7) == 0) {
    int xcd = bid & 7, c = bid >> 3;
    by = xcd*8 + (c & 7);
    bx = c >> 3;
  } else {
    bx = blockIdx.x; by = blockIdx.y;
  }
  int m0 = by * 128, n0 = bx * 128;

  const short* aSrc[4]; const short* bSrc[4];
  {
    int row = w*32 + (lane >> 3);
    int slot = lane & 7;
    #pragma unroll
    for (int c = 0; c < 4; ++c) {
      int r = row + c*8;
      int ga = m0 + r; if (ga > M-1) ga = M-1;
      int gb = n0 + r;
      int sw = slot ^ (r & 7);
      aSrc[c] = A  + (size_t)ga*strideA + sw*8;
      bSrc[c] = Bt + (size_t)gb*strideB + sw*8;
    }
  }

  f32x4 acc[4][4] = {};
  for (int k0 = 0; k0 < K; k0 += 64) {
    #pragma unroll
    for (int c = 0; c < 4; ++c) {
      gload16(aSrc[c] + k0, (short8*)sA + (w*4 + c)*64);
      gload16(bSrc[c] + k0, (short8*)sB + (w*4 + c)*64);
    }
    __syncthreads();
    #pragma unroll
    for (int ks = 0; ks < 2; ++ks) {
      short8 a[4], b[4];
      #pragma unroll
      for (int mf = 0; mf < 4; ++mf) {
        int lr = wm*64 + mf*16 + r15;
        a[mf] = sA[lr][(ks*4 + koct) ^ (lr & 7)];
      }
      #pragma unroll
      for (int nf = 0; nf < 4; ++nf) {
        int lr = wn*64 + nf*16 + r15;
        b[nf] = sB[lr][(ks*4 + koct) ^ (lr & 7)];
      }
      #pragma unroll
      for (int mf = 0; mf < 4; ++mf)
        #pragma unroll
        for (int nf = 0; nf < 4; ++nf)
          acc[mf][nf] = __builtin_amdgcn_mfma_f32_16x16x32_bf16(a[mf], b[nf], acc[mf][nf], 0, 0, 0);
    }
    __syncthreads();
  }
  #pragma unroll
  for (int mf = 0; mf < 4; ++mf) {
    #pragma unroll
    for (int r = 0; r < 4; ++r) {
      int grow = m0 + wm*64 + mf*16 + koct*4 + r;
      if (grow >= M) continue;
      #pragma unroll
      for (int nf = 0; nf < 4; ++nf) {
        int gcol = n0 + wn*64 + nf*16 + r15;
        if (gcol >= N) continue;
        float v = acc[mf][nf][r] + bias[gcol];
        if (EPI == 0) {
          __builtin_nontemporal_store(fast_softplus(v), &Cf[(size_t)grow*strideC + gcol]);
        } else {
          Cb[(size_t)grow*strideCb + gcol] = __float2bfloat16(v);
        }
      }
    }
  }
}

// ---------------- W[k][n] f32 -> Wt[n][k] bf16 (strided rows) -------------
__global__ __launch_bounds__(256) void k_transpose_bf16(
    const float* __restrict__ W, int ldw,
    __hip_bfloat16* __restrict__ Wt, long strideT)
{
  __shared__ float s[64][65];
  int n0 = blockIdx.x * 64, k0 = blockIdx.y * 64;
  int tid = threadIdx.x;
  for (int p = 0; p < 16; ++p) {
    int idx = p*256 + tid;
    int kk = idx >> 6, nn = idx & 63;
    s[kk][nn] = W[(size_t)(k0+kk)*ldw + n0 + nn];
  }
  __syncthreads();
  for (int p = 0; p < 16; ++p) {
    int idx = p*256 + tid;
    int nn = idx >> 6, kk = idx & 63;
    Wt[(size_t)(n0+nn)*strideT + k0 + kk] = __float2bfloat16(s[kk][nn]);
  }
}

// ---------------- K/V f32 -> bf16 ws buffers (V transposed) ---------------
__global__ __launch_bounds__(256) void k_kvcast(
    const float* __restrict__ out, short* __restrict__ Kb, short* __restrict__ Vt)
{
  __shared__ float sV[32][65];
  int tt = blockIdx.x, bh = blockIdx.y;
  int b = bh >> 2, h = bh & 3;
  int tid = threadIdx.x;
  #pragma unroll
  for (int i = 0; i < 8; ++i) {
    int idx = i*256 + tid;
    int tp = idx >> 6, d = idx & 63;
    int t = tt*32 + tp;
    float vv = 0.f;
    if (t < LH) {
      const float* row = out + (size_t)(b*LH + t)*RS;
      Kb[((size_t)bh*511 + t)*64 + d] = bf16b(row[COL_K + h*64 + d]);
      vv = row[COL_V + h*64 + d];
    }
    sV[tp][d] = vv;
  }
  __syncthreads();
  #pragma unroll
  for (int i = 0; i < 8; ++i) {
    int idx = i*256 + tid;
    int d = idx >> 5, tp = idx & 31;
    Vt[((size_t)bh*64 + d)*512 + tt*32 + tp] = bf16b(sV[tp][d]);
  }
}

// ---------------- flash-MFMA attention v1 (fallback, f32 K/V) -------------
__global__ __launch_bounds__(64) void k_attn_mfma(float* __restrict__ out)
{
  int qt = blockIdx.x, h = blockIdx.y, b = blockIdx.z;
  int lane = threadIdx.x & 63;
  int r15 = lane & 15, koct = lane >> 4;
  __shared__ short Vt[64][40];
  __shared__ short Pl[16][40];
  const float* base = out + (size_t)b*LH*RS;

  int qrow = qt*16 + r15; if (qrow > LH-1) qrow = LH-1;
  const float* qp = base + (size_t)qrow*RS + COL_Q + h*64 + koct*8;
  short8 qf[2];
  #pragma unroll
  for (int d2 = 0; d2 < 2; ++d2) {
    f32x4 lo = *(const f32x4*)(qp + d2*32);
    f32x4 hi = *(const f32x4*)(qp + d2*32 + 4);
    short8 t;
    #pragma unroll
    for (int i = 0; i < 4; ++i) { t[i] = bf16b(lo[i]); t[i+4] = bf16b(hi[i]); }
    qf[d2] = t;
  }

  f32x4 o[4] = {};
  float m = -3.0e38f, l = 0.f;
  int qg = qt*16 + r15;
  int nt = qt/2 + 1;

  for (int ti = 0; ti < nt; ++ti) {
    int kv0 = ti*32;
    __syncthreads();
    {
      const float* vbase = base + COL_V + h*64 + lane;
      #pragma unroll 4
      for (int j = 0; j < 32; ++j) {
        int kvr = kv0 + j; if (kvr > LH-1) kvr = LH-1;
        Vt[lane][j] = bf16b(vbase[(size_t)kvr*RS]);
      }
    }
    f32x4 s[2] = {};
    #pragma unroll
    for (int kvf = 0; kvf < 2; ++kvf) {
      int kvr = kv0 + kvf*16 + r15; if (kvr > LH-1) kvr = LH-1;
      const float* kp = base + (size_t)kvr*RS + COL_K + h*64 + koct*8;
      #pragma unroll
      for (int d2 = 0; d2 < 2; ++d2) {
        f32x4 lo = *(const f32x4*)(kp + d2*32);
        f32x4 hi = *(const f32x4*)(kp + d2*32 + 4);
        short8 t;
        #pragma unroll
        for (int i = 0; i < 4; ++i) { t[i] = bf16b(lo[i]); t[i+4] = bf16b(hi[i]); }
        s[kvf] = __builtin_amdgcn_mfma_f32_16x16x32_bf16(t, qf[d2], s[kvf], 0, 0, 0);
      }
    }
    float sv[2][4];
    float mx = -3.0e38f;
    #pragma unroll
    for (int kvf = 0; kvf < 2; ++kvf)
      #pragma unroll
      for (int r = 0; r < 4; ++r) {
        int kvg = kv0 + kvf*16 + koct*4 + r;
        float x = s[kvf][r] * 0.125f;
        if (kvg > qg) x = -3.0e38f;
        sv[kvf][r] = x;
        mx = fmaxf(mx, x);
      }
    mx = fmaxf(mx, __shfl_xor(mx, 16));
    mx = fmaxf(mx, __shfl_xor(mx, 32));
    float mn = fmaxf(m, mx);
    float alpha = expf(m - mn);
    m = mn;
    float ls = 0.f;
    sshort4 pk[2];
    #pragma unroll
    for (int kvf = 0; kvf < 2; ++kvf)
      #pragma unroll
      for (int r = 0; r < 4; ++r) {
        float p = expf(sv[kvf][r] - mn);
        ls += p;
        pk[kvf][r] = bf16b(p);
      }
    l = l*alpha + ls;
    *(sshort4*)&Pl[r15][koct*4]      = pk[0];
    *(sshort4*)&Pl[r15][16 + koct*4] = pk[1];
    __syncthreads();
    float arr[4];
    #pragma unroll
    for (int r = 0; r < 4; ++r) arr[r] = __shfl(alpha, koct*4 + r);
    #pragma unroll
    for (int df = 0; df < 4; ++df)
      #pragma unroll
      for (int r = 0; r < 4; ++r) o[df][r] *= arr[r];
    short8 pa = *(const short8*)&Pl[r15][koct*8];
    #pragma unroll
    for (int df = 0; df < 4; ++df) {
      short8 vb = *(const short8*)&Vt[df*16 + r15][koct*8];
      o[df] = __builtin_amdgcn_mfma_f32_16x16x32_bf16(pa, vb, o[df], 0, 0, 0);
    }
  }
  l += __shfl_xor(l, 16);
  l += __shfl_xor(l, 32);
  float linv = 1.f / l;
  float lr[4];
  #pragma unroll
  for (int r = 0; r < 4; ++r) lr[r] = __shfl(linv, koct*4 + r);
  #pragma unroll
  for (int df = 0; df < 4; ++df)
    #pragma unroll
    for (int r = 0; r < 4; ++r) {
      int qq = qt*16 + koct*4 + r;
      if (qq < LH)
        out[((size_t)(b*LH + qq))*RS + COL_ATTN + h*64 + df*16 + r15] = o[df][r] * lr[r];
    }
}

// ---------------- flash-MFMA attention v2 (bf16 K/Vt in ws) ---------------
__global__ __launch_bounds__(64) void k_attn_mfma2(
    const short* __restrict__ Kb, const short* __restrict__ Vt,
    float* __restrict__ out)
{
  int qt = blockIdx.x, h = blockIdx.y, b = blockIdx.z;
  int lane = threadIdx.x & 63;
  int r15 = lane & 15, koct = lane >> 4;
  __shared__ short Pl[16][40];
  int bh = b*4 + h;
  const short* Kbh = Kb + (size_t)bh*511*64;
  const short* Vbh = Vt + (size_t)bh*64*512;
  const float* base = out + (size_t)b*LH*RS;

  int qrow = qt*16 + r15; if (qrow > LH-1) qrow = LH-1;
  const float* qp = base + (size_t)qrow*RS + COL_Q + h*64 + koct*8;
  short8 qf[2];
  #pragma unroll
  for (int d2 = 0; d2 < 2; ++d2) {
    f32x4 lo = *(const f32x4*)(qp + d2*32);
    f32x4 hi = *(const f32x4*)(qp + d2*32 + 4);
    short8 t;
    #pragma unroll
    for (int i = 0; i < 4; ++i) { t[i] = bf16b(lo[i]); t[i+4] = bf16b(hi[i]); }
    qf[d2] = t;
  }

  f32x4 o[4] = {};
  float m = -3.0e38f, l = 0.f;
  int qg = qt*16 + r15;
  int nt = qt/2 + 1;

  for (int ti = 0; ti < nt; ++ti) {
    int kv0 = ti*32;
    f32x4 s[2] = {};
    #pragma unroll
    for (int kvf = 0; kvf < 2; ++kvf) {
      int kvr = kv0 + kvf*16 + r15; if (kvr > LH-1) kvr = LH-1;
      const short* kp = Kbh + (size_t)kvr*64 + koct*8;
      short8 ka0 = *(const short8*)kp;
      short8 ka1 = *(const short8*)(kp + 32);
      s[kvf] = __builtin_amdgcn_mfma_f32_16x16x32_bf16(ka0, qf[0], s[kvf], 0, 0, 0);
      s[kvf] = __builtin_amdgcn_mfma_f32_16x16x32_bf16(ka1, qf[1], s[kvf], 0, 0, 0);
    }
    float sv[2][4];
    float mx = -3.0e38f;
    #pragma unroll
    for (int kvf = 0; kvf < 2; ++kvf)
      #pragma unroll
      for (int r = 0; r < 4; ++r) {
        int kvg = kv0 + kvf*16 + koct*4 + r;
        float x = s[kvf][r] * 0.125f;
        if (kvg > qg) x = -3.0e38f;
        sv[kvf][r] = x;
        mx = fmaxf(mx, x);
      }
    mx = fmaxf(mx, __shfl_xor(mx, 16));
    mx = fmaxf(mx, __shfl_xor(mx, 32));
    float mn = fmaxf(m, mx);
    float alpha = expf(m - mn);
    m = mn;
    float ls = 0.f;
    sshort4 pk[2];
    #pragma unroll
    for (int kvf = 0; kvf < 2; ++kvf)
      #pragma unroll
      for (int r = 0; r < 4; ++r) {
        float p = expf(sv[kvf][r] - mn);
        ls += p;
        pk[kvf][r] = bf16b(p);
      }
    l = l*alpha + ls;
    *(sshort4*)&Pl[r15][koct*4]      = pk[0];
    *(sshort4*)&Pl[r15][16 + koct*4] = pk[1];
    __syncthreads();   // 1-wave barrier: orders P write->read (cheap)
    float arr[4];
    #pragma unroll
    for (int r = 0; r < 4; ++r) arr[r] = __shfl(alpha, koct*4 + r);
    #pragma unroll
    for (int df = 0; df < 4; ++df)
      #pragma unroll
      for (int r = 0; r < 4; ++r) o[df][r] *= arr[r];
    short8 pa = *(const short8*)&Pl[r15][koct*8];
    #pragma unroll
    for (int df = 0; df < 4; ++df) {
      short8 vb = *(const short8*)(Vbh + (size_t)(df*16 + r15)*512 + kv0 + koct*8);
      o[df] = __builtin_amdgcn_mfma_f32_16x16x32_bf16(pa, vb, o[df], 0, 0, 0);
    }
  }
  l += __shfl_xor(l, 16);
  l += __shfl_xor(l, 32);
  float linv = 1.f / l;
  float lr[4];
  #pragma unroll
  for (int r = 0; r < 4; ++r) lr[r] = __shfl(linv, koct*4 + r);
  #pragma unroll
  for (int df = 0; df < 4; ++df)
    #pragma unroll
    for (int r = 0; r < 4; ++r) {
      int qq = qt*16 + koct*4 + r;
      if (qq < LH)
        out[((size_t)(b*LH + qq))*RS + COL_ATTN + h*64 + df*16 + r15] = o[df][r] * lr[r];
    }
}

// ---------------- flatF[:,512:768]=sub_embed, [:,768:1024]=rel_embed ------
__global__ __launch_bounds__(256) void k_feats(
    const int* __restrict__ subs, const int* __restrict__ marks,
    const float* __restrict__ sub_embed, const float* __restrict__ rel_embed,
    float* __restrict__ out)
{
  int bt = blockIdx.x;
  int b = bt / LH;
  int d = threadIdx.x;
  out[(size_t)bt*RS + COL_FF + 512 + d] = sub_embed[(size_t)subs[b*L_]*256 + d];
  out[(size_t)bt*RS + COL_FF + 768 + d] = rel_embed[(size_t)marks[b*L_]*256 + d];
}

// ---------------- fused segment-mean + gp projection (no atomics) ---------
__global__ __launch_bounds__(256) void k_seg2(
    const int* __restrict__ subs, const int* __restrict__ marks,
    const void* __restrict__ mask, const int* __restrict__ group_map,
    const float* __restrict__ gp_w, const float* __restrict__ gp_b,
    float* __restrict__ out)
{
  __shared__ unsigned char match[512];
  __shared__ float macc[1024];
  __shared__ float pacc[4][64];
  __shared__ int cnt;
  int key = blockIdx.x;            // b*64 + g
  int b = key >> 6, g = key & 63;
  int tid = threadIdx.x;
  int boolmode = ((const int*)out)[COL_FLAG];
  if (tid == 0) cnt = 0;
  __syncthreads();
  int lc = 0;
  for (int t = tid; t < LH; t += 256) {
    int mt = 0;
    if (mask_at(mask, b*L_ + t, boolmode)) {
      int gid = group_map[subs[b*L_ + t]*NRELS + marks[b*L_ + t]];
      mt = (gid == g) ? 1 : 0;
    }
    match[t] = (unsigned char)mt;
    lc += mt;
  }
  if (lc) atomicAdd(&cnt, lc);     // LDS int add: exact, order-free
  __syncthreads();

  f32x4 acc = {0.f, 0.f, 0.f, 0.f};
  int c0 = tid * 4;
  for (int t = 0; t < LH; ++t) {
    if (match[t]) {
      f32x4 v = *(const f32x4*)(out + (size_t)(b*LH + t)*RS + COL_FF + c0);
      acc.x += v.x; acc.y += v.y; acc.z += v.z; acc.w += v.w;
    }
  }
  *(f32x4*)&macc[c0] = acc;
  __syncthreads();

  int j = tid & 63, ch = tid >> 6;
  float p = 0.f;
  int kb = ch * 256;
  for (int k2 = kb; k2 < kb + 256; ++k2)
    p += macc[k2] * gp_w[k2*GPDIM + j];
  pacc[ch][j] = p;
  __syncthreads();
  if (tid < 64) {
    float inv = 1.0f / fmaxf((float)cnt, 1.0f);
    float s = pacc[0][tid] + pacc[1][tid] + pacc[2][tid] + pacc[3][tid];
    out[(size_t)key*RS + COL_GP + tid] = s * inv + gp_b[tid];
  }
}

// ---------------- whole group transformer per batch, all in LDS -----------
__global__ __launch_bounds__(256) void k_group(
    const float* __restrict__ ga_in_w, const float* __restrict__ ga_in_b,
    const float* __restrict__ ga_out_w, const float* __restrict__ ga_out_b,
    const float* __restrict__ ffn_w1, const float* __restrict__ ffn_b1,
    const float* __restrict__ ffn_w2, const float* __restrict__ ffn_b2,
    const float* __restrict__ n1_w, const float* __restrict__ n1_b,
    const float* __restrict__ n2_w, const float* __restrict__ n2_b,
    float* __restrict__ out)
{
  __shared__ float sGP[64][64];
  __shared__ float sQ[64][64];
  __shared__ float sK[64][64];
  __shared__ float sV[64][64];
  int b = blockIdx.x, tid = threadIdx.x;
  for (int i = tid; i < 4096; i += 256)
    sGP[i>>6][i&63] = out[(size_t)(b*64 + (i>>6))*RS + COL_GP + (i&63)];
  __syncthreads();
  for (int i = tid; i < 64*192; i += 256) {
    int g = i / 192, c = i - g*192;
    float acc = ga_in_b[c];
    for (int k2 = 0; k2 < 64; ++k2) acc += sGP[g][k2] * ga_in_w[k2*192 + c];
    if (c < 64)       sQ[g][c]      = acc;
    else if (c < 128) sK[g][c-64]   = acc;
    else              sV[g][c-128]  = acc;
  }
  __syncthreads();
  if (tid < 128) {
    int qi = tid >> 1, h = tid & 1, base = h*32;
    float sc[64];
    float mx = -3.0e38f;
    #pragma unroll
    for (int k2 = 0; k2 < 64; ++k2) {
      float d2 = 0.f;
      #pragma unroll
      for (int d = 0; d < 32; ++d) d2 += sQ[qi][base+d] * sK[k2][base+d];
      d2 *= 0.17677669529663689f;
      sc[k2] = d2;
      mx = fmaxf(mx, d2);
    }
    float den = 0.f;
    #pragma unroll
    for (int k2 = 0; k2 < 64; ++k2) { sc[k2] = expf(sc[k2]-mx); den += sc[k2]; }
    float inv = 1.f/den;
    #pragma unroll
    for (int d = 0; d < 32; ++d) {
      float acc = 0.f;
      #pragma unroll
      for (int k2 = 0; k2 < 64; ++k2) acc += sc[k2] * sV[k2][base+d];
      sQ[qi][base+d] = acc * inv;
    }
  }
  __syncthreads();
  for (int i = tid; i < 4096; i += 256) {
    int g = i>>6, c = i&63;
    float acc = ga_out_b[c];
    for (int k2 = 0; k2 < 64; ++k2) acc += sQ[g][k2] * ga_out_w[k2*64 + c];
    sK[g][c] = sGP[g][c] + acc;
  }
  __syncthreads();
  if (tid < 64) {
    int g = tid;
    float mu = 0.f; for (int c=0;c<64;c++) mu += sK[g][c]; mu *= (1.f/64.f);
    float var = 0.f; for (int c=0;c<64;c++){float d2=sK[g][c]-mu; var += d2*d2;} var *= (1.f/64.f);
    float inv = 1.0f / sqrtf(var + 1e-5f);
    for (int c=0;c<64;c++) sK[g][c] = (sK[g][c]-mu)*inv*n1_w[c] + n1_b[c];
  }
  __syncthreads();
  for (int i = tid; i < 4096; i += 256) {
    int g = i>>6, c = i&63;
    float acc = ffn_b1[c];
    for (int k2 = 0; k2 < 64; ++k2) acc += sK[g][k2] * ffn_w1[k2*64 + c];
    sV[g][c] = fmaxf(acc, 0.f);
  }
  __syncthreads();
  for (int i = tid; i < 4096; i += 256) {
    int g = i>>6, c = i&63;
    float acc = ffn_b2[c];
    for (int k2 = 0; k2 < 64; ++k2) acc += sV[g][k2] * ffn_w2[k2*64 + c];
    sGP[g][c] = sK[g][c] + acc;
  }
  __syncthreads();
  if (tid < 64) {
    int g = tid;
    float mu = 0.f; for (int c=0;c<64;c++) mu += sGP[g][c]; mu *= (1.f/64.f);
    float var = 0.f; for (int c=0;c<64;c++){float d2=sGP[g][c]-mu; var += d2*d2;} var *= (1.f/64.f);
    float inv = 1.0f / sqrtf(var + 1e-5f);
    for (int c=0;c<64;c++)
      out[(size_t)(b*64 + g)*RS + COL_GOUT + c] = (sGP[g][c]-mu)*inv*n2_w[c] + n2_b[c];
  }
}

// ---------------- fused gather + merged-A bf16 cast ------------------------
__global__ __launch_bounds__(256) void k_gather_cast(
    const int* __restrict__ subs, const int* __restrict__ marks,
    const void* __restrict__ mask, const int* __restrict__ group_map,
    float* __restrict__ out)
{
  __shared__ float gv[64];
  int bt = blockIdx.x;
  int b = bt / LH, t = bt - b*LH;
  int tid = threadIdx.x;
  int boolmode = ((const int*)out)[COL_FLAG];
  if (tid < 64) {
    float val = 0.f;
    if (mask_at(mask, b*L_ + t, boolmode)) {
      int gid = group_map[subs[b*L_+t]*NRELS + marks[b*L_+t]];
      val = out[(size_t)(b*NG + gid)*RS + COL_GOUT + tid];
    }
    gv[tid] = val;
  }
  __syncthreads();
  const float* src = out + (size_t)bt*RS + COL_FF;
  short* dst = (short*)out + (size_t)bt*RS2 + BCOL_MGA;
  for (int i = tid; i < 1088; i += 256)
    dst[i] = bf16b(i < 1024 ? src[i] : gv[i - 1024]);
}

// ---------------- tail v6 (fallback when ws too small) --------------------
__global__ __launch_bounds__(256) void k_tail_v6(
    const float* __restrict__ int_w, const float* __restrict__ int_b,
    float* __restrict__ out)
{
  __shared__ short8 sA[16][128];
  __shared__ short8 sB[2][128][8];
  int m0 = blockIdx.x * 16;
  int tid = threadIdx.x;
  int lane = tid & 63;
  int w = tid >> 6;
  int r15 = lane & 15, koct = lane >> 4;
  const short* eb = (const short*)out + BCOL_ENH;

  for (int idx = tid; idx < 16*128; idx += 256) {
    int r = idx >> 7, c8 = idx & 127;
    int row = m0 + r; if (row > RTOT-1) row = RTOT-1;
    sA[r][c8 ^ (r & 7)] = *(const short8*)(eb + (size_t)row*RS2 + c8*8);
  }

  int tn2 = tid & 63;
  int tk4 = tid >> 6;
  int xA = r15 & 7;

  f32x2 v[16];
  auto issueB = [&](int s) {
    int ntile = s >> 4, ks = s & 15;
    int nb = N1 + ntile*128 + tn2*2;
    int ncl = nb <= NENT-2 ? nb : NENT-2;
    const float* bp = int_w + (size_t)(ks*64 + tk4*16)*NENT + ncl;
    #pragma unroll
    for (int i = 0; i < 16; ++i) v[i] = *(const f32x2*)(bp + (size_t)i*NENT);
  };

  issueB(0);
  __syncthreads();

  f32x4 acc[2] = {};
  for (int s = 0; s < 144; ++s) {
    int ks = s & 15;
    int buf = s & 1;
    {
      short h0[16], h1[16];
      #pragma unroll
      for (int i = 0; i < 16; ++i) { h0[i] = bf16b(v[i][0]); h1[i] = bf16b(v[i][1]); }
      short8 p0lo, p0hi, p1lo, p1hi;
      #pragma unroll
      for (int i = 0; i < 8; ++i) {
        p0lo[i] = h0[i]; p0hi[i] = h0[i+8];
        p1lo[i] = h1[i]; p1hi[i] = h1[i+8];
      }
      int nl0 = tn2*2, nl1 = tn2*2 + 1;
      sB[buf][nl0][(tk4*2 + 0) ^ (nl0 & 7)] = p0lo;
      sB[buf][nl0][(tk4*2 + 1) ^ (nl0 & 7)] = p0hi;
      sB[buf][nl1][(tk4*2 + 0) ^ (nl1 & 7)] = p1lo;
      sB[buf][nl1][(tk4*2 + 1) ^ (nl1 & 7)] = p1hi;
    }
    if (s + 1 < 144) issueB(s + 1);
    __syncthreads();
    #pragma unroll
    for (int ksub = 0; ksub < 2; ++ksub) {
      int c8A = ks*8 + ksub*4 + koct;
      short8 a0 = sA[r15][c8A ^ xA];
      #pragma unroll
      for (int nf = 0; nf < 2; ++nf) {
        int nloc = w*32 + nf*16 + r15;
        short8 b = sB[buf][nloc][(ksub*4 + koct) ^ (nloc & 7)];
        acc[nf] = __builtin_amdgcn_mfma_f32_16x16x32_bf16(a0, b, acc[nf], 0, 0, 0);
      }
    }
    if (ks == 15) {
      int n0 = N1 + (s >> 4)*128;
      #pragma unroll
      for (int nf = 0; nf < 2; ++nf) {
        int n = n0 + w*32 + nf*16 + r15;
        if (n < NENT) {
          float bv = int_b[n];
          #pragma unroll
          for (int r = 0; r < 4; ++r) {
            int g = m0 + koct*4 + r;
            if (g < RTOT)
              __builtin_nontemporal_store(fast_softplus(acc[nf][r] + bv),
                                          &out[(size_t)g*RS + n]);
          }
        }
        acc[nf] = (f32x4){0.f, 0.f, 0.f, 0.f};
      }
    }
  }
}

// ---------------- tail v8: B pre-transposed bf16 in d_ws (v1 layout) ------
__global__ __launch_bounds__(256) void k_tail_v8(
    const short* __restrict__ Bt, const float* __restrict__ int_b,
    float* __restrict__ out)
{
  __shared__ short8 sA[16][128];
  __shared__ short8 sB[2][128][8];
  int m0 = blockIdx.x * 16;
  int tid = threadIdx.x;
  int lane = tid & 63;
  int w = tid >> 6;
  int r15 = lane & 15, koct = lane >> 4;
  const short* eb = (const short*)out + BCOL_ENH;

  for (int idx = tid; idx < 16*128; idx += 256) {
    int r = idx >> 7, c8 = idx & 127;
    int row = m0 + r; if (row > RTOT-1) row = RTOT-1;
    sA[r][c8 ^ (r & 7)] = *(const short8*)(eb + (size_t)row*RS2 + c8*8);
  }

  int rl8 = w*8 + (lane >> 3);
  int slot = lane & 7;
  int xA = r15 & 7;

  auto issueB = [&](int s) {
    int ntile = s >> 4, ks = s & 15;
    #pragma unroll
    for (int c = 0; c < 4; ++c) {
      int rowL = c*32 + rl8;
      int wsrow = ntile*128 + rowL;
      if (wsrow > 1087) wsrow = 1087;
      int sw = slot ^ (rowL & 7);
      gload16(Bt + (size_t)wsrow*1024 + ks*64 + sw*8,
              (short8*)&sB[s & 1][c*32 + w*8][0]);
    }
  };

  issueB(0);
  __syncthreads();

  f32x4 acc[2] = {};
  for (int s = 0; s < 144; ++s) {
    int ks = s & 15, buf = s & 1;
    if (s + 1 < 144) issueB(s + 1);
    #pragma unroll
    for (int ksub = 0; ksub < 2; ++ksub) {
      int c8A = ks*8 + ksub*4 + koct;
      short8 a0 = sA[r15][c8A ^ xA];
      #pragma unroll
      for (int nf = 0; nf < 2; ++nf) {
        int nloc = w*32 + nf*16 + r15;
        short8 b = sB[buf][nloc][(ksub*4 + koct) ^ (nloc & 7)];
        acc[nf] = __builtin_amdgcn_mfma_f32_16x16x32_bf16(a0, b, acc[nf], 0, 0, 0);
      }
    }
    if (ks == 15) {
      int n0 = N1 + (s >> 4)*128;
      #pragma unroll
      for (int nf = 0; nf < 2; ++nf) {
        int n = n0 + w*32 + nf*16 + r15;
        if (n < NENT) {
          float bv = int_b[n];
          #pragma unroll
          for (int r = 0; r < 4; ++r) {
            int g = m0 + koct*4 + r;
            if (g < RTOT)
              __builtin_nontemporal_store(fast_softplus(acc[nf][r] + bv),
                                          &out[(size_t)g*RS + n]);
          }
        }
        acc[nf] = (f32x4){0.f, 0.f, 0.f, 0.f};
      }
    }
    __syncthreads();
  }
}

extern "C" void kernel_launch(void* const* d_in, const int* in_sizes, int n_in,
                              void* d_out, int out_size, void* d_ws, size_t ws_size,
                              hipStream_t stream)
{
  const int*   subs      = (const int*)  d_in[0];
  const int*   marks     = (const int*)  d_in[1];
  const int*   objs      = (const int*)  d_in[2];
  const float* times     = (const float*)d_in[3];
  const float* dts       = (const float*)d_in[4];
  const void*  mask      =               d_in[5];
  const int*   group_map = (const int*)  d_in[6];
  const float* obj_embed = (const float*)d_in[7];
  const float* Wq        = (const float*)d_in[8];
  const float* Wk        = (const float*)d_in[9];
  const float* Wv        = (const float*)d_in[10];
  const float* Wo        = (const float*)d_in[11];
  const float* sub_embed = (const float*)d_in[12];
  const float* rel_embed = (const float*)d_in[13];
  const float* gp_w      = (const float*)d_in[14];
  const float* gp_b      = (const float*)d_in[15];
  const float* ga_in_w   = (const float*)d_in[16];
  const float* ga_in_b   = (const float*)d_in[17];
  const float* ga_out_w  = (const float*)d_in[18];
  const float* ga_out_b  = (const float*)d_in[19];
  const float* ffn_w1    = (const float*)d_in[20];
  const float* ffn_b1    = (const float*)d_in[21];
  const float* ffn_w2    = (const float*)d_in[22];
  const float* ffn_b2    = (const float*)d_in[23];
  const float* n1_w      = (const float*)d_in[24];
  const float* n1_b      = (const float*)d_in[25];
  const float* n2_w      = (const float*)d_in[26];
  const float* n2_b      = (const float*)d_in[27];
  const float* mg_w      = (const float*)d_in[28];
  const float* mg_b      = (const float*)d_in[29];
  const float* int_w     = (const float*)d_in[30];
  const float* int_b     = (const float*)d_in[31];
  float* out = (float*)d_out;
  __hip_bfloat16* ob = (__hip_bfloat16*)d_out;

  bool ws_ok  = ws_size >= (size_t)1088 * 1024 * sizeof(__hip_bfloat16);
  bool ws_ok2 = ws_size >= WS_NEED2;
  bool ws_ok3 = ws_size >= WS_NEED3;

  short* wsK = ws_ok3 ? (short*)((char*)d_ws + WS2_K) : (short*)((char*)d_ws + WS_OFF_K);
  short* wsV = ws_ok3 ? (short*)((char*)d_ws + WS2_V) : (short*)((char*)d_ws + WS_OFF_V);
  __hip_bfloat16* wsENH = (__hip_bfloat16*)((char*)d_ws + WS2_ENH);

  k_detect<<<1, 256, 0, stream>>>((const unsigned int*)mask, out);
  k_transpose_bf16<<<dim3(N1/64, DFEAT/64), 256, 0, stream>>>(int_w, NENT, ob + BCOL_WT, RS2);
  k_transpose_bf16<<<dim3(DFEAT/64, 1088/64), 256, 0, stream>>>(mg_w, DFEAT, ob + BCOL_MGWT, RS2);
  if (ws_ok) {
    // tail Bt: stride WSP (padded) in v2 layout, 1024 in v1 layout
    k_transpose_bf16<<<dim3(1088/64, DFEAT/64), 256, 0, stream>>>(
        int_w + N1, NENT, (__hip_bfloat16*)d_ws, ws_ok3 ? WSP : 1024);
  }
  for (int l = 0; l < 2; ++l) {
    const float* ws[4] = { Wq + (size_t)l*DM*DM, Wk + (size_t)l*DM*DM,
                           Wv + (size_t)l*DM*DM, Wo + (size_t)l*DM*DM };
    for (int j = 0; j < 4; ++j)
      k_transpose_bf16<<<dim3(4, 4), 256, 0, stream>>>(
          ws[j], DM, ob + BCOL_ENCW + (size_t)((l*4 + j)*256)*RS2, RS2);
  }

  k_build_x_cur<<<RTOT, 256, 0, stream>>>(objs, times, dts, obj_embed, out);

  for (int l = 0; l < 2; ++l) {
    const short* encw = (const short*)(ob + BCOL_ENCW);
    const short* wtq = encw + (size_t)((l*4 + 0)*256)*RS2;
    const short* wtk = encw + (size_t)((l*4 + 1)*256)*RS2;
    const short* wto = encw + (size_t)((l*4 + 3)*256)*RS2;
    gemm_mfma<true, 3><<<dim3(2, 64), 256, 0, stream>>>(
        out + COL_CUR, RS, wtq, RS2, nullptr,
        out + COL_Q, RS, nullptr, 0, nullptr, 0, 0, RTOT, DM);
    gemm_mfma<true, 3><<<dim3(4, 64), 256, 0, stream>>>(
        out + COL_X, RS, wtk, RS2, nullptr,
        out + COL_K, RS, nullptr, 0, nullptr, 0, 0, RTOT, DM);
    if (ws_ok2) {
      k_kvcast<<<dim3(16, 64), 256, 0, stream>>>(out, wsK, wsV);
      k_attn_mfma2<<<dim3(32, 4, B_), 64, 0, stream>>>(wsK, wsV, out);
    } else {
      k_attn_mfma<<<dim3(32, 4, B_), 64, 0, stream>>>(out);
    }
    gemm_mfma<true, 2><<<dim3(2, 64), 256, 0, stream>>>(
        out + COL_ATTN, RS, wto, RS2, nullptr,
        out + COL_CUR, RS, nullptr, 0, out + COL_FF, RS, l*DM, RTOT, DM);
  }

  k_feats<<<RTOT, 256, 0, stream>>>(subs, marks, sub_embed, rel_embed, out);
  k_seg2<<<1024, 256, 0, stream>>>(subs, marks, mask, group_map, gp_w, gp_b, out);
  k_group<<<B_, 256, 0, stream>>>(ga_in_w, ga_in_b, ga_out_w, ga_out_b,
                                  ffn_w1, ffn_b1, ffn_w2, ffn_b2,
                                  n1_w, n1_b, n2_w, n2_b, out);
  k_gather_cast<<<RTOT, 256, 0, stream>>>(subs, marks, mask, group_map, out);

  if (ws_ok3) {
    gemm_mfma_lds<1><<<dim3(DFEAT/128, 64), 256, 0, stream>>>(
        (const short*)(ob + BCOL_MGA), RS2, (const short*)(ob + BCOL_MGWT), RS2, mg_b,
        nullptr, 0, wsENH, WSP, RTOT, DFEAT, 1088);
    gemm_mfma_lds<0><<<dim3(N1/128, (RTOT+127)/128), 256, 0, stream>>>(
        (const short*)wsENH, WSP, (const short*)(ob + BCOL_WT), RS2, int_b,
        out, RS, nullptr, 0, RTOT, N1, DFEAT);
    gemm_mfma_lds<0><<<dim3(9, 64), 256, 0, stream>>>(
        (const short*)wsENH, WSP, (const short*)d_ws, WSP, int_b + N1,
        out + N1, RS, nullptr, 0, RTOT, 1088, DFEAT);
  } else {
    gemm_mfma_lds<1><<<dim3(DFEAT/128, 64), 256, 0, stream>>>(
        (const short*)(ob + BCOL_MGA), RS2, (const short*)(ob + BCOL_MGWT), RS2, mg_b,
        nullptr, 0, ob + BCOL_ENH, RS2, RTOT, DFEAT, 1088);
    gemm_mfma_lds<0><<<dim3(N1/128, (RTOT+127)/128), 256, 0, stream>>>(
        (const short*)(ob + BCOL_ENH), RS2, (const short*)(ob + BCOL_WT), RS2, int_b,
        out, RS, nullptr, 0, RTOT, N1, DFEAT);
    if (ws_ok)
      k_tail_v8<<<RTOT/16, 256, 0, stream>>>((const short*)d_ws, int_b, out);
    else
      k_tail_v6<<<RTOT/16, 256, 0, stream>>>(int_w, int_b, out);
  }
}